// Round 2
// baseline (420.352 us; speedup 1.0000x reference)
//
#include <hip/hip_runtime.h>
#include <hip/hip_bf16.h>
#include <math.h>

// Problem constants (fixed by reference)
#define BATCH 2
#define SEQ   2048
#define DMODEL 2048
#define NHEADS 16
#define HDIM  128
#define MROWS (BATCH * SEQ)   // 4096

typedef __attribute__((ext_vector_type(8))) short short8;
typedef __attribute__((ext_vector_type(8))) unsigned short ushort8;
typedef __attribute__((ext_vector_type(4))) float f32x4;

static __device__ __forceinline__ unsigned short f2bf(float x) {
    __hip_bfloat16 h = __float2bfloat16(x);
    return __builtin_bit_cast(unsigned short, h);
}

static __device__ __forceinline__ void async_load16(const void* g, void* l) {
    __builtin_amdgcn_global_load_lds(
        (const __attribute__((address_space(1))) unsigned int*)g,
        (__attribute__((address_space(3))) unsigned int*)l, 16, 0, 0);
}

// ---------------------------------------------------------------------------
// fp32 -> bf16 elementwise convert (x)
// ---------------------------------------------------------------------------
__global__ __launch_bounds__(256) void convert_bf16_kernel(
    const float* __restrict__ in, unsigned short* __restrict__ out, int n)
{
    const int idx = (blockIdx.x * 256 + threadIdx.x) * 4;
    if (idx < n) {
        const float4 v = *(const float4*)(in + idx);
        ushort4 u;
        u.x = f2bf(v.x); u.y = f2bf(v.y); u.z = f2bf(v.z); u.w = f2bf(v.w);
        *(ushort4*)(out + idx) = u;
    }
}

// ---------------------------------------------------------------------------
// Fused transpose of wq,wk,wv: [K,N] fp32 -> [N,K] bf16 into 3 Wt slots.
// ---------------------------------------------------------------------------
__global__ __launch_bounds__(256) void transpose3_bf16_kernel(
    const float* __restrict__ w0, const float* __restrict__ w1,
    const float* __restrict__ w2, unsigned short* __restrict__ WtAll)
{
    const float* W = blockIdx.z == 0 ? w0 : (blockIdx.z == 1 ? w1 : w2);
    unsigned short* Wt = WtAll + (size_t)blockIdx.z * DMODEL * DMODEL;

    __shared__ float T[64][65];
    const int tid = threadIdx.x;
    const int tr  = tid >> 4;
    const int tc4 = (tid & 15) * 4;
    const int k0 = blockIdx.y * 64;
    const int n0 = blockIdx.x * 64;

    #pragma unroll
    for (int i = 0; i < 4; ++i) {
        const int kr = i * 16 + tr;
        const float4 v = *(const float4*)(W + (size_t)(k0 + kr) * DMODEL + n0 + tc4);
        T[kr][tc4 + 0] = v.x; T[kr][tc4 + 1] = v.y;
        T[kr][tc4 + 2] = v.z; T[kr][tc4 + 3] = v.w;
    }
    __syncthreads();
    #pragma unroll
    for (int i = 0; i < 4; ++i) {
        const int nr = i * 16 + tr;
        ushort4 u;
        u.x = f2bf(T[tc4 + 0][nr]); u.y = f2bf(T[tc4 + 1][nr]);
        u.z = f2bf(T[tc4 + 2][nr]); u.w = f2bf(T[tc4 + 3][nr]);
        *(ushort4*)(Wt + (size_t)(n0 + nr) * DMODEL + k0 + tc4) = u;
    }
}

// single transpose (for wo)
__global__ __launch_bounds__(256) void transpose_bf16_kernel(
    const float* __restrict__ W, unsigned short* __restrict__ Wt, int K, int N)
{
    __shared__ float T[64][65];
    const int tid = threadIdx.x;
    const int tr  = tid >> 4;
    const int tc4 = (tid & 15) * 4;
    const int k0 = blockIdx.y * 64;
    const int n0 = blockIdx.x * 64;

    #pragma unroll
    for (int i = 0; i < 4; ++i) {
        const int kr = i * 16 + tr;
        const float4 v = *(const float4*)(W + (size_t)(k0 + kr) * N + n0 + tc4);
        T[kr][tc4 + 0] = v.x; T[kr][tc4 + 1] = v.y;
        T[kr][tc4 + 2] = v.z; T[kr][tc4 + 3] = v.w;
    }
    __syncthreads();
    #pragma unroll
    for (int i = 0; i < 4; ++i) {
        const int nr = i * 16 + tr;
        ushort4 u;
        u.x = f2bf(T[tc4 + 0][nr]); u.y = f2bf(T[tc4 + 1][nr]);
        u.z = f2bf(T[tc4 + 2][nr]); u.w = f2bf(T[tc4 + 3][nr]);
        *(ushort4*)(Wt + (size_t)(n0 + nr) * K + k0 + tc4) = u;
    }
}

// ---------------------------------------------------------------------------
// Fused QKV GEMM — 128x256 tile, BK=64, 8 waves (2M x 4N, wave-tile 64x64),
// grid 768 = EXACTLY 3 dispatch rounds on 256 CUs (no tail; the 256^2 version
// at 384 blocks wasted 25% on round quantization).
//
// 2-phase/K-tile schedule:
//   ph1: read ALL 16 frags (8 B + 8 A ds_read_b128); barrier; lgkmcnt(0);
//        setprio; 16 MFMA (m0-1); barrier.
//   ph2: stage ALL 6 units of tile t+2 (every LDS region's last read was ph1,
//        so every region is recyclable here); setprio; 16 MFMA (m2-3);
//        vmcnt(6); barrier.
// Steady state: 12 loads in flight, counted vmcnt(6) once per K-tile retires
// exactly tile t+1's 6 units (issued a full 3 phases earlier -> latency
// hidden). Never drains to 0 in the main loop.
// T2 XOR-granule swizzle both-sides (pre-swizzled global src + swizzled
// ds_read) — verified 0 bank conflicts in round 1.
// T1 XCD swizzle: 768 % 8 == 0, chunk = 96; bx fastest -> each XCD owns a
// 512-row A band (2 MB, L2-resident) and streams B through L3.
// ---------------------------------------------------------------------------
__global__ __launch_bounds__(512, 2) void qkv_gemm_kernel(
    const unsigned short* __restrict__ A, const unsigned short* __restrict__ WtAll,
    const float* __restrict__ bq, const float* __restrict__ bk,
    const float* __restrict__ bv,
    unsigned short* __restrict__ Qb, unsigned short* __restrict__ Kb,
    unsigned short* __restrict__ Vt)
{
    constexpr int K  = DMODEL;   // 2048
    constexpr int NT = K / 64;   // 32 K-tiles

    __shared__ __align__(16) unsigned short As[2][128 * 64];   // 32 KB
    __shared__ __align__(16) unsigned short Bs[2][256 * 64];   // 64 KB

    const int tid  = threadIdx.x;
    const int lane = tid & 63;
    const int wave = tid >> 6;      // 0..7
    const int ln15 = lane & 15;
    const int quad = lane >> 4;
    const int wr   = wave >> 2;     // 0..1  (M half)
    const int wc   = wave & 3;      // 0..3  (N quarter)

    // XCD-aware bijective swizzle (nwg=768, 96 per XCD)
    const int bid = (blockIdx.x & 7) * 96 + (blockIdx.x >> 3);
    const int bx  = bid % 24;              // N tile (fastest within XCD chunk)
    const int by  = bid / 24;              // M tile
    const int bm   = by * 128;
    const int bn   = bx * 256;             // 0..5888
    const int widx = bn >> 11;             // 0=Q 1=K 2=V
    const int bnl  = bn & 2047;

    const unsigned short* Bt = WtAll + (size_t)widx * DMODEL * DMODEL;
    const float* bias = widx == 0 ? bq : (widx == 1 ? bk : bv);

    // ---- staging: thread -> (row sr within unit, swizzled source granule) ----
    const int sr = tid >> 3;                 // 0..63
    const int sg = (tid & 7) ^ (sr & 7);     // XOR swizzle (involution)
    const unsigned short* Ag = A  + (size_t)(bm  + sr) * K + sg * 8;
    const unsigned short* Bg = Bt + (size_t)(bnl + sr) * K + sg * 8;

    // ---- ds_read offsets (ushort units); physical granule = logical ^ (row&7)
    const int swz0 = ((0 + quad) ^ (ln15 & 7)) * 8;   // ks=0 granules 0..3
    const int swz1 = ((4 + quad) ^ (ln15 & 7)) * 8;   // ks=1 granules 4..7
    const int arow = (wr * 64 + ln15) * 64;           // + mp*1024
    const int brow = (wc * 64 + ln15) * 64;           // + np*1024

#define STAGE_A(c, q, k0) async_load16(Ag + (size_t)(q) * 64 * K + (k0), \
                                       &As[c][(q) * 4096 + wave * 512])
#define STAGE_B(c, q, k0) async_load16(Bg + (size_t)(q) * 64 * K + (k0), \
                                       &Bs[c][(q) * 4096 + wave * 512])

    f32x4 acc[4][4];
    #pragma unroll
    for (int i = 0; i < 4; ++i)
        #pragma unroll
        for (int j = 0; j < 4; ++j) acc[i][j] = (f32x4){0.f, 0.f, 0.f, 0.f};

    // ---- prologue: tiles 0 and 1 fully staged (6 units each) ----
    STAGE_A(0, 0, 0); STAGE_A(0, 1, 0);
    STAGE_B(0, 0, 0); STAGE_B(0, 1, 0); STAGE_B(0, 2, 0); STAGE_B(0, 3, 0);
    STAGE_A(1, 0, 64); STAGE_A(1, 1, 64);
    STAGE_B(1, 0, 64); STAGE_B(1, 1, 64); STAGE_B(1, 2, 64); STAGE_B(1, 3, 64);
    asm volatile("s_waitcnt vmcnt(6)" ::: "memory");   // tile 0 landed
    __builtin_amdgcn_s_barrier();

    short8 af[4][2];
    short8 bfr[4][2];

    #pragma unroll 2
    for (int t = 0; t < NT; ++t) {
        const int c  = t & 1;
        const int k2 = (t + 2) * 64;
        const unsigned short* Ac = As[c];
        const unsigned short* Bc = Bs[c];

        // ---- phase 1: read ALL frags; MFMA m0-1 ----
        #pragma unroll
        for (int np = 0; np < 4; ++np) {
            bfr[np][0] = *(const short8*)(Bc + brow + np * 1024 + swz0);
            bfr[np][1] = *(const short8*)(Bc + brow + np * 1024 + swz1);
        }
        #pragma unroll
        for (int mp = 0; mp < 4; ++mp) {
            af[mp][0] = *(const short8*)(Ac + arow + mp * 1024 + swz0);
            af[mp][1] = *(const short8*)(Ac + arow + mp * 1024 + swz1);
        }
        __builtin_amdgcn_s_barrier();
        asm volatile("s_waitcnt lgkmcnt(0)" ::: "memory");
        __builtin_amdgcn_sched_barrier(0);
        __builtin_amdgcn_s_setprio(1);
        #pragma unroll
        for (int ks = 0; ks < 2; ++ks)
            #pragma unroll
            for (int mt = 0; mt < 2; ++mt)
                #pragma unroll
                for (int nt = 0; nt < 4; ++nt)
                    acc[mt][nt] = __builtin_amdgcn_mfma_f32_16x16x32_bf16(
                        af[mt][ks], bfr[nt][ks], acc[mt][nt], 0, 0, 0);
        __builtin_amdgcn_s_setprio(0);
        __builtin_amdgcn_s_barrier();

        // ---- phase 2: stage all of tile t+2; MFMA m2-3 (pure reg) ----
        if (t + 2 < NT) {
            STAGE_A(c, 0, k2); STAGE_A(c, 1, k2);
            STAGE_B(c, 0, k2); STAGE_B(c, 1, k2);
            STAGE_B(c, 2, k2); STAGE_B(c, 3, k2);
        }
        __builtin_amdgcn_s_setprio(1);
        #pragma unroll
        for (int ks = 0; ks < 2; ++ks)
            #pragma unroll
            for (int mt = 2; mt < 4; ++mt)
                #pragma unroll
                for (int nt = 0; nt < 4; ++nt)
                    acc[mt][nt] = __builtin_amdgcn_mfma_f32_16x16x32_bf16(
                        af[mt][ks], bfr[nt][ks], acc[mt][nt], 0, 0, 0);
        __builtin_amdgcn_s_setprio(0);
        if (t + 2 < NT) { asm volatile("s_waitcnt vmcnt(6)" ::: "memory"); }
        else            { asm volatile("s_waitcnt vmcnt(0)" ::: "memory"); }
        __builtin_amdgcn_s_barrier();
    }

#undef STAGE_A
#undef STAGE_B

    // ---- epilogue ----
    if (widx == 2) {
        #pragma unroll
        for (int mp = 0; mp < 4; ++mp) {
            const int m0 = bm + wr * 64 + mp * 16 + quad * 4;
            const int bb = m0 >> 11;
            const int s0 = m0 & 2047;
            #pragma unroll
            for (int np = 0; np < 4; ++np) {
                const int col = bnl + wc * 64 + np * 16 + ln15;
                const float bvv = bias[col];
                ushort4 pk;
                pk.x = f2bf(acc[mp][np][0] + bvv);
                pk.y = f2bf(acc[mp][np][1] + bvv);
                pk.z = f2bf(acc[mp][np][2] + bvv);
                pk.w = f2bf(acc[mp][np][3] + bvv);
                *(ushort4*)(Vt + ((size_t)(bb * 16 + (col >> 7)) * 128 + (col & 127)) * SEQ + s0) = pk;
            }
        }
    } else {
        unsigned short* dst = widx ? Kb : Qb;
        #pragma unroll
        for (int mp = 0; mp < 4; ++mp)
            #pragma unroll
            for (int r = 0; r < 4; ++r) {
                const int row = bm + wr * 64 + mp * 16 + quad * 4 + r;
                #pragma unroll
                for (int np = 0; np < 4; ++np) {
                    const int col = bnl + wc * 64 + np * 16 + ln15;
                    dst[(size_t)row * DMODEL + col] = f2bf(acc[mp][np][r] + bias[col]);
                }
            }
    }
}

// ---------------------------------------------------------------------------
// Out-projection MFMA GEMM (fp32 out), m97 structure.
// ---------------------------------------------------------------------------
__global__ __launch_bounds__(256) void gemm_out_kernel(
    const unsigned short* __restrict__ A, const unsigned short* __restrict__ Bt,
    const float* __restrict__ bias, float* __restrict__ C, int M, int N, int K)
{
    __shared__ __align__(16) unsigned short As[128 * 32];
    __shared__ __align__(16) unsigned short Bs[128 * 32];

    const int tid  = threadIdx.x;
    const int lane = tid & 63;
    const int wave = tid >> 6;
    const int ln15 = lane & 15;
    const int quad = lane >> 4;
    const int wm = (wave & 1) * 64;
    const int wn = (wave >> 1) * 64;
    const int bm = blockIdx.y * 128;
    const int bn = blockIdx.x * 128;

    const int srow = tid >> 2;
    const int scol = (tid & 3) * 8;

    const unsigned short* Ap = A  + (size_t)(bm + srow) * K + scol;
    const unsigned short* Bp = Bt + (size_t)(bn + srow) * K + scol;

    f32x4 acc[4][4];
    #pragma unroll
    for (int i = 0; i < 4; ++i)
        #pragma unroll
        for (int j = 0; j < 4; ++j) acc[i][j] = (f32x4){0.f, 0.f, 0.f, 0.f};

    for (int k0 = 0; k0 < K; k0 += 32) {
        __syncthreads();
        async_load16(Ap + k0,                    As + wave * 512);
        async_load16(Ap + (size_t)64 * K + k0,   As + 2048 + wave * 512);
        async_load16(Bp + k0,                    Bs + wave * 512);
        async_load16(Bp + (size_t)64 * K + k0,   Bs + 2048 + wave * 512);
        __syncthreads();

        short8 af[4], bf[4];
        #pragma unroll
        for (int mt = 0; mt < 4; ++mt)
            af[mt] = *(const short8*)(&As[(wm + mt * 16 + ln15) * 32 + quad * 8]);
        #pragma unroll
        for (int nt = 0; nt < 4; ++nt)
            bf[nt] = *(const short8*)(&Bs[(wn + nt * 16 + ln15) * 32 + quad * 8]);
        #pragma unroll
        for (int mt = 0; mt < 4; ++mt)
            #pragma unroll
            for (int nt = 0; nt < 4; ++nt)
                acc[mt][nt] = __builtin_amdgcn_mfma_f32_16x16x32_bf16(
                    af[mt], bf[nt], acc[mt][nt], 0, 0, 0);
    }

    #pragma unroll
    for (int mt = 0; mt < 4; ++mt)
        #pragma unroll
        for (int r = 0; r < 4; ++r) {
            const int row = bm + wm + mt * 16 + quad * 4 + r;
            #pragma unroll
            for (int nt = 0; nt < 4; ++nt) {
                const int col = bn + wn + nt * 16 + ln15;
                C[(size_t)row * N + col] = acc[mt][nt][r] + bias[col];
            }
        }
}

// ---------------------------------------------------------------------------
// MFMA flash attention — LDS-staged, double-buffered, pair-balanced,
// fast-path/diagonal split, XCD-pinned (blocks of one head ≡ same id mod 32
// -> same XCD under round-robin dispatch).
// ---------------------------------------------------------------------------
#define ATT_P_STRIDE 40

__global__ __launch_bounds__(256) void attn_kernel(
    const unsigned short* __restrict__ Qb, const unsigned short* __restrict__ Kb,
    const unsigned short* __restrict__ Vt,   // [B*H][HDIM][SEQ]
    unsigned short* __restrict__ O)
{
    __shared__ __align__(16) unsigned short Ks[2][32 * 128];
    __shared__ __align__(16) unsigned short Vs[2][128 * 32];
    __shared__ __align__(16) unsigned short Pl[4 * 16 * ATT_P_STRIDE];

    const int tid  = threadIdx.x;
    const int lane = tid & 63;
    const int wave = tid >> 6;
    const int ln15 = lane & 15;
    const int quad = lane >> 4;

    // XCD pinning: id = j*32 + g, g = head-group (b,h), j = q-pair index
    const int g = blockIdx.x & 31;
    const int jj = blockIdx.x >> 5;        // 0..15
    const int h = g & 15;
    const int b = g >> 4;

    const size_t rowbase = (size_t)b * SEQ;
    const size_t hoff    = (size_t)h * HDIM;
    const unsigned short* Kh  = Kb + rowbase * DMODEL + hoff;
    const unsigned short* Vth = Vt + (size_t)(b * NHEADS + h) * HDIM * SEQ;

    const float sc2     = 0.08838834764831845f * 1.4426950408889634f;
    const float slope2  = exp2f(-0.5f * (float)(h + 1)) * 1.4426950408889634f;
    const float slope16 = slope2 * 16.0f;
    const float slope32 = slope2 * 32.0f;

    // staging lane roles
    const int kq  = wave * 8 + (lane >> 4);
    const int ksl = lane & 15;
    const int dq  = wave * 32 + (lane >> 2);
    const int vsl = lane & 3;
    const int vsw = (ln15 >> 1) & 3;

    unsigned short* Pw = &Pl[wave * 16 * ATT_P_STRIDE];

    #pragma unroll 1
    for (int ph = 0; ph < 2; ++ph) {
        const int qblk = ph ? (31 - jj) : jj;
        const int q0w  = qblk * 64 + wave * 16;
        const int nT   = 2 * qblk + 2;

        short8 qf[4];
        {
            const unsigned short* qp =
                Qb + (rowbase + q0w + ln15) * DMODEL + hoff + quad * 8;
            qf[0] = *(const short8*)(qp);
            qf[1] = *(const short8*)(qp + 32);
            qf[2] = *(const short8*)(qp + 64);
            qf[3] = *(const short8*)(qp + 96);
        }

        f32x4 acc[8];
        #pragma unroll
        for (int nt = 0; nt < 8; ++nt) acc[nt] = (f32x4){0.f, 0.f, 0.f, 0.f};
        float lsum[4] = {0.f, 0.f, 0.f, 0.f};

        // incremental ALiBi bias: c0[r] = slope2*(kb+ln15 - (q0w+quad*4+r))
        float c0[4];
        {
            const float base = slope2 * (float)(ln15 - q0w - quad * 4);
            #pragma unroll
            for (int r = 0; r < 4; ++r) c0[r] = base - slope2 * (float)r;
        }

        // ---- stage tile 0 into buffer 0 ----
        #pragma unroll
        for (int i = 0; i < 2; ++i) {
            const int k = kq + i * 4;
            async_load16(Kh + (size_t)k * DMODEL + (ksl ^ (k & 15)) * 8,
                         &Ks[0][(wave * 8 + i * 4) * 128]);
        }
        #pragma unroll
        for (int i = 0; i < 2; ++i) {
            const int d = dq + i * 16;
            async_load16(Vth + (size_t)d * SEQ + (vsl ^ ((d >> 1) & 3)) * 8,
                         &Vs[0][(wave * 32 + i * 16) * 32]);
        }
        __syncthreads();

        for (int t = 0; t < nT; ++t) {
            const int kb  = t * 32;
            const int buf = t & 1;

            if (t + 1 < nT) {
                const int kb1 = kb + 32;
                #pragma unroll
                for (int i = 0; i < 2; ++i) {
                    const int k = kq + i * 4;
                    async_load16(Kh + (size_t)(kb1 + k) * DMODEL + (ksl ^ (k & 15)) * 8,
                                 &Ks[buf ^ 1][(wave * 8 + i * 4) * 128]);
                }
                #pragma unroll
                for (int i = 0; i < 2; ++i) {
                    const int d = dq + i * 16;
                    async_load16(Vth + (size_t)d * SEQ + kb1 + (vsl ^ ((d >> 1) & 3)) * 8,
                                 &Vs[buf ^ 1][(wave * 32 + i * 16) * 32]);
                }
            }

            if (kb <= q0w + 15) {
                const unsigned short* KsB = Ks[buf];
                const unsigned short* VsB = Vs[buf];

                f32x4 s0 = (f32x4){0.f,0.f,0.f,0.f}, s1 = (f32x4){0.f,0.f,0.f,0.f};
                #pragma unroll
                for (int c = 0; c < 4; ++c) {
                    const int slot = (c * 4 + quad) ^ ln15;
                    short8 kf0 = *(const short8*)(&KsB[ln15 * 128 + slot * 8]);
                    short8 kf1 = *(const short8*)(&KsB[(16 + ln15) * 128 + slot * 8]);
                    s0 = __builtin_amdgcn_mfma_f32_16x16x32_bf16(qf[c], kf0, s0, 0, 0, 0);
                    s1 = __builtin_amdgcn_mfma_f32_16x16x32_bf16(qf[c], kf1, s1, 0, 0, 0);
                }

                float p0[4], p1[4];
                if (kb + 31 <= q0w) {
                    // fully unmasked fast path
                    #pragma unroll
                    for (int r = 0; r < 4; ++r) {
                        p0[r] = exp2f(fmaf(s0[r], sc2, c0[r]));
                        p1[r] = exp2f(fmaf(s1[r], sc2, c0[r] + slope16));
                        lsum[r] += p0[r] + p1[r];
                    }
                } else {
                    // diagonal tile: per-element causal mask
                    #pragma unroll
                    for (int r = 0; r < 4; ++r) {
                        const int qrow = q0w + quad * 4 + r;
                        const int k0i = kb + ln15;
                        const float e0 = exp2f(fmaf(s0[r], sc2, c0[r]));
                        const float e1 = exp2f(fmaf(s1[r], sc2, c0[r] + slope16));
                        p0[r] = (k0i      <= qrow) ? e0 : 0.f;
                        p1[r] = (k0i + 16 <= qrow) ? e1 : 0.f;
                        lsum[r] += p0[r] + p1[r];
                    }
                }

                #pragma unroll
                for (int r = 0; r < 4; ++r) {
                    Pw[(quad * 4 + r) * ATT_P_STRIDE + ln15]      = f2bf(p0[r]);
                    Pw[(quad * 4 + r) * ATT_P_STRIDE + 16 + ln15] = f2bf(p1[r]);
                }
                __builtin_amdgcn_s_waitcnt(0xC07F);   // lgkmcnt(0)
                short8 pf = *(const short8*)(&Pw[ln15 * ATT_P_STRIDE + quad * 8]);

                #pragma unroll
                for (int nt = 0; nt < 8; ++nt) {
                    short8 vf = *(const short8*)(
                        &VsB[(nt * 16 + ln15) * 32 + (quad ^ vsw) * 8]);
                    acc[nt] = __builtin_amdgcn_mfma_f32_16x16x32_bf16(pf, vf, acc[nt], 0, 0, 0);
                }
            }

            #pragma unroll
            for (int r = 0; r < 4; ++r) c0[r] += slope32;
            __syncthreads();
        }

        #pragma unroll
        for (int r = 0; r < 4; ++r) {
            float l = lsum[r];
            l += __shfl_xor(l, 1, 64);
            l += __shfl_xor(l, 2, 64);
            l += __shfl_xor(l, 4, 64);
            l += __shfl_xor(l, 8, 64);
            const float inv = 1.0f / l;
            const size_t ob = (rowbase + q0w + quad * 4 + r) * DMODEL + hoff;
            #pragma unroll
            for (int nt = 0; nt < 8; ++nt)
                O[ob + nt * 16 + ln15] = f2bf(acc[nt][r] * inv);
        }
    }
}

// ---------------------------------------------------------------------------
extern "C" void kernel_launch(void* const* d_in, const int* in_sizes, int n_in,
                              void* d_out, int out_size, void* d_ws, size_t ws_size,
                              hipStream_t stream)
{
    const float* x  = (const float*)d_in[0];
    const float* wq = (const float*)d_in[1];
    const float* bq = (const float*)d_in[2];
    const float* wk = (const float*)d_in[3];
    const float* bk = (const float*)d_in[4];
    const float* wv = (const float*)d_in[5];
    const float* bv = (const float*)d_in[6];
    const float* wo = (const float*)d_in[7];
    const float* bo = (const float*)d_in[8];
    float* out = (float*)d_out;

    const size_t bufElems = (size_t)MROWS * DMODEL;   // 8.39M
    unsigned short* Qb  = (unsigned short*)d_ws;
    unsigned short* Kb  = Qb + bufElems;
    unsigned short* Vtg = Kb + bufElems;      // V^T: [B*H][HDIM][SEQ]
    unsigned short* xb  = Vtg + bufElems;     // x bf16; later reused as Ob
    unsigned short* Ob  = xb;                 // alias (xb dead after QKV GEMM)
    unsigned short* Wt  = xb + bufElems;      // 3 slots of 2048*2048 bf16

    const dim3 blk(256);

    convert_bf16_kernel<<<dim3((int)(bufElems / 1024)), blk, 0, stream>>>(
        x, xb, (int)bufElems);

    transpose3_bf16_kernel<<<dim3(32, 32, 3), blk, 0, stream>>>(wq, wk, wv, Wt);

    qkv_gemm_kernel<<<dim3(768), dim3(512), 0, stream>>>(
        xb, Wt, bq, bk, bv, Qb, Kb, Vtg);

    // wo -> Wt slot 0 (QKV GEMM has consumed it by stream order)
    transpose_bf16_kernel<<<dim3(32, 32), blk, 0, stream>>>(wo, Wt, DMODEL, DMODEL);

    attn_kernel<<<dim3(512), blk, 0, stream>>>(Qb, Kb, Vtg, Ob);

    gemm_out_kernel<<<dim3(16, 32), blk, 0, stream>>>(
        Ob, Wt, bo, out, MROWS, DMODEL, DMODEL);
}

// Round 3
// 390.493 us; speedup vs baseline: 1.0765x; 1.0765x over previous
//
#include <hip/hip_runtime.h>
#include <hip/hip_bf16.h>
#include <math.h>

// Problem constants (fixed by reference)
#define BATCH 2
#define SEQ   2048
#define DMODEL 2048
#define NHEADS 16
#define HDIM  128
#define MROWS (BATCH * SEQ)   // 4096

typedef __attribute__((ext_vector_type(8))) short short8;
typedef __attribute__((ext_vector_type(8))) unsigned short ushort8;
typedef __attribute__((ext_vector_type(4))) float f32x4;

static __device__ __forceinline__ unsigned short f2bf(float x) {
    __hip_bfloat16 h = __float2bfloat16(x);
    return __builtin_bit_cast(unsigned short, h);
}

static __device__ __forceinline__ void async_load16(const void* g, void* l) {
    __builtin_amdgcn_global_load_lds(
        (const __attribute__((address_space(1))) unsigned int*)g,
        (__attribute__((address_space(3))) unsigned int*)l, 16, 0, 0);
}

// ---------------------------------------------------------------------------
// fp32 -> bf16 elementwise convert (x)
// ---------------------------------------------------------------------------
__global__ __launch_bounds__(256) void convert_bf16_kernel(
    const float* __restrict__ in, unsigned short* __restrict__ out, int n)
{
    const int idx = (blockIdx.x * 256 + threadIdx.x) * 4;
    if (idx < n) {
        const float4 v = *(const float4*)(in + idx);
        ushort4 u;
        u.x = f2bf(v.x); u.y = f2bf(v.y); u.z = f2bf(v.z); u.w = f2bf(v.w);
        *(ushort4*)(out + idx) = u;
    }
}

// ---------------------------------------------------------------------------
// Fused transpose of wq,wk,wv: [K,N] fp32 -> [N,K] bf16 into 3 Wt slots.
// ---------------------------------------------------------------------------
__global__ __launch_bounds__(256) void transpose3_bf16_kernel(
    const float* __restrict__ w0, const float* __restrict__ w1,
    const float* __restrict__ w2, unsigned short* __restrict__ WtAll)
{
    const float* W = blockIdx.z == 0 ? w0 : (blockIdx.z == 1 ? w1 : w2);
    unsigned short* Wt = WtAll + (size_t)blockIdx.z * DMODEL * DMODEL;

    __shared__ float T[64][65];
    const int tid = threadIdx.x;
    const int tr  = tid >> 4;
    const int tc4 = (tid & 15) * 4;
    const int k0 = blockIdx.y * 64;
    const int n0 = blockIdx.x * 64;

    #pragma unroll
    for (int i = 0; i < 4; ++i) {
        const int kr = i * 16 + tr;
        const float4 v = *(const float4*)(W + (size_t)(k0 + kr) * DMODEL + n0 + tc4);
        T[kr][tc4 + 0] = v.x; T[kr][tc4 + 1] = v.y;
        T[kr][tc4 + 2] = v.z; T[kr][tc4 + 3] = v.w;
    }
    __syncthreads();
    #pragma unroll
    for (int i = 0; i < 4; ++i) {
        const int nr = i * 16 + tr;
        ushort4 u;
        u.x = f2bf(T[tc4 + 0][nr]); u.y = f2bf(T[tc4 + 1][nr]);
        u.z = f2bf(T[tc4 + 2][nr]); u.w = f2bf(T[tc4 + 3][nr]);
        *(ushort4*)(Wt + (size_t)(n0 + nr) * DMODEL + k0 + tc4) = u;
    }
}

// single transpose (for wo)
__global__ __launch_bounds__(256) void transpose_bf16_kernel(
    const float* __restrict__ W, unsigned short* __restrict__ Wt, int K, int N)
{
    __shared__ float T[64][65];
    const int tid = threadIdx.x;
    const int tr  = tid >> 4;
    const int tc4 = (tid & 15) * 4;
    const int k0 = blockIdx.y * 64;
    const int n0 = blockIdx.x * 64;

    #pragma unroll
    for (int i = 0; i < 4; ++i) {
        const int kr = i * 16 + tr;
        const float4 v = *(const float4*)(W + (size_t)(k0 + kr) * N + n0 + tc4);
        T[kr][tc4 + 0] = v.x; T[kr][tc4 + 1] = v.y;
        T[kr][tc4 + 2] = v.z; T[kr][tc4 + 3] = v.w;
    }
    __syncthreads();
    #pragma unroll
    for (int i = 0; i < 4; ++i) {
        const int nr = i * 16 + tr;
        ushort4 u;
        u.x = f2bf(T[tc4 + 0][nr]); u.y = f2bf(T[tc4 + 1][nr]);
        u.z = f2bf(T[tc4 + 2][nr]); u.w = f2bf(T[tc4 + 3][nr]);
        *(ushort4*)(Wt + (size_t)(n0 + nr) * K + k0 + tc4) = u;
    }
}

// ---------------------------------------------------------------------------
// Fused QKV GEMM — 128x256 tile, BK=64, 8 waves (2M x 4N, wave-tile 64x64),
// grid 768 = exactly 3 dispatch rounds. 2-phase counted-vmcnt schedule,
// T2 XOR swizzle (0 bank conflicts measured), T1 XCD swizzle. Unchanged from
// round 2 (131 us, per-block eff 31.5%).
// ---------------------------------------------------------------------------
__global__ __launch_bounds__(512, 2) void qkv_gemm_kernel(
    const unsigned short* __restrict__ A, const unsigned short* __restrict__ WtAll,
    const float* __restrict__ bq, const float* __restrict__ bk,
    const float* __restrict__ bv,
    unsigned short* __restrict__ Qb, unsigned short* __restrict__ Kb,
    unsigned short* __restrict__ Vt)
{
    constexpr int K  = DMODEL;   // 2048
    constexpr int NT = K / 64;   // 32 K-tiles

    __shared__ __align__(16) unsigned short As[2][128 * 64];   // 32 KB
    __shared__ __align__(16) unsigned short Bs[2][256 * 64];   // 64 KB

    const int tid  = threadIdx.x;
    const int lane = tid & 63;
    const int wave = tid >> 6;      // 0..7
    const int ln15 = lane & 15;
    const int quad = lane >> 4;
    const int wr   = wave >> 2;     // 0..1  (M half)
    const int wc   = wave & 3;      // 0..3  (N quarter)

    // XCD-aware bijective swizzle (nwg=768, 96 per XCD)
    const int bid = (blockIdx.x & 7) * 96 + (blockIdx.x >> 3);
    const int bx  = bid % 24;              // N tile (fastest within XCD chunk)
    const int by  = bid / 24;              // M tile
    const int bm   = by * 128;
    const int bn   = bx * 256;             // 0..5888
    const int widx = bn >> 11;             // 0=Q 1=K 2=V
    const int bnl  = bn & 2047;

    const unsigned short* Bt = WtAll + (size_t)widx * DMODEL * DMODEL;
    const float* bias = widx == 0 ? bq : (widx == 1 ? bk : bv);

    // ---- staging: thread -> (row sr within unit, swizzled source granule) ----
    const int sr = tid >> 3;                 // 0..63
    const int sg = (tid & 7) ^ (sr & 7);     // XOR swizzle (involution)
    const unsigned short* Ag = A  + (size_t)(bm  + sr) * K + sg * 8;
    const unsigned short* Bg = Bt + (size_t)(bnl + sr) * K + sg * 8;

    // ---- ds_read offsets (ushort units); physical granule = logical ^ (row&7)
    const int swz0 = ((0 + quad) ^ (ln15 & 7)) * 8;   // ks=0 granules 0..3
    const int swz1 = ((4 + quad) ^ (ln15 & 7)) * 8;   // ks=1 granules 4..7
    const int arow = (wr * 64 + ln15) * 64;           // + mp*1024
    const int brow = (wc * 64 + ln15) * 64;           // + np*1024

#define STAGE_A(c, q, k0) async_load16(Ag + (size_t)(q) * 64 * K + (k0), \
                                       &As[c][(q) * 4096 + wave * 512])
#define STAGE_B(c, q, k0) async_load16(Bg + (size_t)(q) * 64 * K + (k0), \
                                       &Bs[c][(q) * 4096 + wave * 512])

    f32x4 acc[4][4];
    #pragma unroll
    for (int i = 0; i < 4; ++i)
        #pragma unroll
        for (int j = 0; j < 4; ++j) acc[i][j] = (f32x4){0.f, 0.f, 0.f, 0.f};

    // ---- prologue: tiles 0 and 1 fully staged (6 units each) ----
    STAGE_A(0, 0, 0); STAGE_A(0, 1, 0);
    STAGE_B(0, 0, 0); STAGE_B(0, 1, 0); STAGE_B(0, 2, 0); STAGE_B(0, 3, 0);
    STAGE_A(1, 0, 64); STAGE_A(1, 1, 64);
    STAGE_B(1, 0, 64); STAGE_B(1, 1, 64); STAGE_B(1, 2, 64); STAGE_B(1, 3, 64);
    asm volatile("s_waitcnt vmcnt(6)" ::: "memory");   // tile 0 landed
    __builtin_amdgcn_s_barrier();

    short8 af[4][2];
    short8 bfr[4][2];

    #pragma unroll 2
    for (int t = 0; t < NT; ++t) {
        const int c  = t & 1;
        const int k2 = (t + 2) * 64;
        const unsigned short* Ac = As[c];
        const unsigned short* Bc = Bs[c];

        // ---- phase 1: read ALL frags; MFMA m0-1 ----
        #pragma unroll
        for (int np = 0; np < 4; ++np) {
            bfr[np][0] = *(const short8*)(Bc + brow + np * 1024 + swz0);
            bfr[np][1] = *(const short8*)(Bc + brow + np * 1024 + swz1);
        }
        #pragma unroll
        for (int mp = 0; mp < 4; ++mp) {
            af[mp][0] = *(const short8*)(Ac + arow + mp * 1024 + swz0);
            af[mp][1] = *(const short8*)(Ac + arow + mp * 1024 + swz1);
        }
        __builtin_amdgcn_s_barrier();
        asm volatile("s_waitcnt lgkmcnt(0)" ::: "memory");
        __builtin_amdgcn_sched_barrier(0);
        __builtin_amdgcn_s_setprio(1);
        #pragma unroll
        for (int ks = 0; ks < 2; ++ks)
            #pragma unroll
            for (int mt = 0; mt < 2; ++mt)
                #pragma unroll
                for (int nt = 0; nt < 4; ++nt)
                    acc[mt][nt] = __builtin_amdgcn_mfma_f32_16x16x32_bf16(
                        af[mt][ks], bfr[nt][ks], acc[mt][nt], 0, 0, 0);
        __builtin_amdgcn_s_setprio(0);
        __builtin_amdgcn_s_barrier();

        // ---- phase 2: stage all of tile t+2; MFMA m2-3 (pure reg) ----
        if (t + 2 < NT) {
            STAGE_A(c, 0, k2); STAGE_A(c, 1, k2);
            STAGE_B(c, 0, k2); STAGE_B(c, 1, k2);
            STAGE_B(c, 2, k2); STAGE_B(c, 3, k2);
        }
        __builtin_amdgcn_s_setprio(1);
        #pragma unroll
        for (int ks = 0; ks < 2; ++ks)
            #pragma unroll
            for (int mt = 2; mt < 4; ++mt)
                #pragma unroll
                for (int nt = 0; nt < 4; ++nt)
                    acc[mt][nt] = __builtin_amdgcn_mfma_f32_16x16x32_bf16(
                        af[mt][ks], bfr[nt][ks], acc[mt][nt], 0, 0, 0);
        __builtin_amdgcn_s_setprio(0);
        if (t + 2 < NT) { asm volatile("s_waitcnt vmcnt(6)" ::: "memory"); }
        else            { asm volatile("s_waitcnt vmcnt(0)" ::: "memory"); }
        __builtin_amdgcn_s_barrier();
    }

#undef STAGE_A
#undef STAGE_B

    // ---- epilogue ----
    if (widx == 2) {
        #pragma unroll
        for (int mp = 0; mp < 4; ++mp) {
            const int m0 = bm + wr * 64 + mp * 16 + quad * 4;
            const int bb = m0 >> 11;
            const int s0 = m0 & 2047;
            #pragma unroll
            for (int np = 0; np < 4; ++np) {
                const int col = bnl + wc * 64 + np * 16 + ln15;
                const float bvv = bias[col];
                ushort4 pk;
                pk.x = f2bf(acc[mp][np][0] + bvv);
                pk.y = f2bf(acc[mp][np][1] + bvv);
                pk.z = f2bf(acc[mp][np][2] + bvv);
                pk.w = f2bf(acc[mp][np][3] + bvv);
                *(ushort4*)(Vt + ((size_t)(bb * 16 + (col >> 7)) * 128 + (col & 127)) * SEQ + s0) = pk;
            }
        }
    } else {
        unsigned short* dst = widx ? Kb : Qb;
        #pragma unroll
        for (int mp = 0; mp < 4; ++mp)
            #pragma unroll
            for (int r = 0; r < 4; ++r) {
                const int row = bm + wr * 64 + mp * 16 + quad * 4 + r;
                #pragma unroll
                for (int np = 0; np < 4; ++np) {
                    const int col = bnl + wc * 64 + np * 16 + ln15;
                    dst[(size_t)row * DMODEL + col] = f2bf(acc[mp][np][r] + bias[col]);
                }
            }
    }
}

// ---------------------------------------------------------------------------
// Out-projection GEMM — same 128x256 BK=64 2-phase counted-vmcnt structure as
// qkv_gemm_kernel (proven this session), fp32 epilogue. N=2048 -> grid
// 8 bx x 32 by = 256 blocks = EXACTLY 1 round on 256 CUs (no tail at all).
// XCD mapping: bx = id&7 -> each XCD's 32 concurrent blocks share one 1 MB
// B panel (L2-resident); A streams through L3.
// ---------------------------------------------------------------------------
__global__ __launch_bounds__(512, 2) void gemm_out256_kernel(
    const unsigned short* __restrict__ A, const unsigned short* __restrict__ Bt,
    const float* __restrict__ bias, float* __restrict__ C)
{
    constexpr int K  = DMODEL;   // 2048
    constexpr int N  = DMODEL;   // 2048
    constexpr int NT = K / 64;   // 32 K-tiles

    __shared__ __align__(16) unsigned short As[2][128 * 64];   // 32 KB
    __shared__ __align__(16) unsigned short Bs[2][256 * 64];   // 64 KB

    const int tid  = threadIdx.x;
    const int lane = tid & 63;
    const int wave = tid >> 6;      // 0..7
    const int ln15 = lane & 15;
    const int quad = lane >> 4;
    const int wr   = wave >> 2;     // 0..1  (M half)
    const int wc   = wave & 3;      // 0..3  (N quarter)

    const int bx = blockIdx.x & 7;         // N tile (XCD-pinned)
    const int by = blockIdx.x >> 3;        // M tile
    const int bm = by * 128;
    const int bn = bx * 256;

    const int sr = tid >> 3;
    const int sg = (tid & 7) ^ (sr & 7);
    const unsigned short* Ag = A  + (size_t)(bm + sr) * K + sg * 8;
    const unsigned short* Bg = Bt + (size_t)(bn + sr) * K + sg * 8;

    const int swz0 = ((0 + quad) ^ (ln15 & 7)) * 8;
    const int swz1 = ((4 + quad) ^ (ln15 & 7)) * 8;
    const int arow = (wr * 64 + ln15) * 64;
    const int brow = (wc * 64 + ln15) * 64;

#define STAGE_A(c, q, k0) async_load16(Ag + (size_t)(q) * 64 * K + (k0), \
                                       &As[c][(q) * 4096 + wave * 512])
#define STAGE_B(c, q, k0) async_load16(Bg + (size_t)(q) * 64 * K + (k0), \
                                       &Bs[c][(q) * 4096 + wave * 512])

    f32x4 acc[4][4];
    #pragma unroll
    for (int i = 0; i < 4; ++i)
        #pragma unroll
        for (int j = 0; j < 4; ++j) acc[i][j] = (f32x4){0.f, 0.f, 0.f, 0.f};

    STAGE_A(0, 0, 0); STAGE_A(0, 1, 0);
    STAGE_B(0, 0, 0); STAGE_B(0, 1, 0); STAGE_B(0, 2, 0); STAGE_B(0, 3, 0);
    STAGE_A(1, 0, 64); STAGE_A(1, 1, 64);
    STAGE_B(1, 0, 64); STAGE_B(1, 1, 64); STAGE_B(1, 2, 64); STAGE_B(1, 3, 64);
    asm volatile("s_waitcnt vmcnt(6)" ::: "memory");
    __builtin_amdgcn_s_barrier();

    short8 af[4][2];
    short8 bfr[4][2];

    #pragma unroll 2
    for (int t = 0; t < NT; ++t) {
        const int c  = t & 1;
        const int k2 = (t + 2) * 64;
        const unsigned short* Ac = As[c];
        const unsigned short* Bc = Bs[c];

        #pragma unroll
        for (int np = 0; np < 4; ++np) {
            bfr[np][0] = *(const short8*)(Bc + brow + np * 1024 + swz0);
            bfr[np][1] = *(const short8*)(Bc + brow + np * 1024 + swz1);
        }
        #pragma unroll
        for (int mp = 0; mp < 4; ++mp) {
            af[mp][0] = *(const short8*)(Ac + arow + mp * 1024 + swz0);
            af[mp][1] = *(const short8*)(Ac + arow + mp * 1024 + swz1);
        }
        __builtin_amdgcn_s_barrier();
        asm volatile("s_waitcnt lgkmcnt(0)" ::: "memory");
        __builtin_amdgcn_sched_barrier(0);
        __builtin_amdgcn_s_setprio(1);
        #pragma unroll
        for (int ks = 0; ks < 2; ++ks)
            #pragma unroll
            for (int mt = 0; mt < 2; ++mt)
                #pragma unroll
                for (int nt = 0; nt < 4; ++nt)
                    acc[mt][nt] = __builtin_amdgcn_mfma_f32_16x16x32_bf16(
                        af[mt][ks], bfr[nt][ks], acc[mt][nt], 0, 0, 0);
        __builtin_amdgcn_s_setprio(0);
        __builtin_amdgcn_s_barrier();

        if (t + 2 < NT) {
            STAGE_A(c, 0, k2); STAGE_A(c, 1, k2);
            STAGE_B(c, 0, k2); STAGE_B(c, 1, k2);
            STAGE_B(c, 2, k2); STAGE_B(c, 3, k2);
        }
        __builtin_amdgcn_s_setprio(1);
        #pragma unroll
        for (int ks = 0; ks < 2; ++ks)
            #pragma unroll
            for (int mt = 2; mt < 4; ++mt)
                #pragma unroll
                for (int nt = 0; nt < 4; ++nt)
                    acc[mt][nt] = __builtin_amdgcn_mfma_f32_16x16x32_bf16(
                        af[mt][ks], bfr[nt][ks], acc[mt][nt], 0, 0, 0);
        __builtin_amdgcn_s_setprio(0);
        if (t + 2 < NT) { asm volatile("s_waitcnt vmcnt(6)" ::: "memory"); }
        else            { asm volatile("s_waitcnt vmcnt(0)" ::: "memory"); }
        __builtin_amdgcn_s_barrier();
    }

#undef STAGE_A
#undef STAGE_B

    #pragma unroll
    for (int mp = 0; mp < 4; ++mp)
        #pragma unroll
        for (int r = 0; r < 4; ++r) {
            const int row = bm + wr * 64 + mp * 16 + quad * 4 + r;
            #pragma unroll
            for (int np = 0; np < 4; ++np) {
                const int col = bn + wc * 64 + np * 16 + ln15;
                C[(size_t)row * N + col] = acc[mp][np][r] + bias[col];
            }
        }
}

// ---------------------------------------------------------------------------
// MFMA flash attention — LDS-staged, double-buffered, fast-path/diagonal
// split, XCD-pinned (id&31 -> same head-group on same XCD -> K/V L2-resident).
// Round 3: 1024 single-qblk blocks (was 512 paired) -> 4 blocks/CU residency
// (16 waves/CU) to hide the serial QK->softmax->P-LDS->PV chain; long blocks
// (qblk 31) dispatched first so the dynamic scheduler backfills the tail.
// ---------------------------------------------------------------------------
#define ATT_P_STRIDE 40

__global__ __launch_bounds__(256, 4) void attn_kernel(
    const unsigned short* __restrict__ Qb, const unsigned short* __restrict__ Kb,
    const unsigned short* __restrict__ Vt,   // [B*H][HDIM][SEQ]
    unsigned short* __restrict__ O)
{
    __shared__ __align__(16) unsigned short Ks[2][32 * 128];
    __shared__ __align__(16) unsigned short Vs[2][128 * 32];
    __shared__ __align__(16) unsigned short Pl[4 * 16 * ATT_P_STRIDE];

    const int tid  = threadIdx.x;
    const int lane = tid & 63;
    const int wave = tid >> 6;
    const int ln15 = lane & 15;
    const int quad = lane >> 4;

    // XCD pinning: id = j*32 + g, g = head-group (b,h); long qblks first
    const int g = blockIdx.x & 31;
    const int qblk = 31 - (blockIdx.x >> 5);   // 0..31, descending issue
    const int h = g & 15;
    const int b = g >> 4;

    const size_t rowbase = (size_t)b * SEQ;
    const size_t hoff    = (size_t)h * HDIM;
    const unsigned short* Kh  = Kb + rowbase * DMODEL + hoff;
    const unsigned short* Vth = Vt + (size_t)(b * NHEADS + h) * HDIM * SEQ;

    const float sc2     = 0.08838834764831845f * 1.4426950408889634f;
    const float slope2  = exp2f(-0.5f * (float)(h + 1)) * 1.4426950408889634f;
    const float slope16 = slope2 * 16.0f;
    const float slope32 = slope2 * 32.0f;

    // staging lane roles
    const int kq  = wave * 8 + (lane >> 4);
    const int ksl = lane & 15;
    const int dq  = wave * 32 + (lane >> 2);
    const int vsl = lane & 3;
    const int vsw = (ln15 >> 1) & 3;

    unsigned short* Pw = &Pl[wave * 16 * ATT_P_STRIDE];

    const int q0w  = qblk * 64 + wave * 16;
    const int nT   = 2 * qblk + 2;

    short8 qf[4];
    {
        const unsigned short* qp =
            Qb + (rowbase + q0w + ln15) * DMODEL + hoff + quad * 8;
        qf[0] = *(const short8*)(qp);
        qf[1] = *(const short8*)(qp + 32);
        qf[2] = *(const short8*)(qp + 64);
        qf[3] = *(const short8*)(qp + 96);
    }

    f32x4 acc[8];
    #pragma unroll
    for (int nt = 0; nt < 8; ++nt) acc[nt] = (f32x4){0.f, 0.f, 0.f, 0.f};
    float lsum[4] = {0.f, 0.f, 0.f, 0.f};

    // incremental ALiBi bias: c0[r] = slope2*(kb+ln15 - (q0w+quad*4+r))
    float c0[4];
    {
        const float base = slope2 * (float)(ln15 - q0w - quad * 4);
        #pragma unroll
        for (int r = 0; r < 4; ++r) c0[r] = base - slope2 * (float)r;
    }

    // ---- stage tile 0 into buffer 0 ----
    #pragma unroll
    for (int i = 0; i < 2; ++i) {
        const int k = kq + i * 4;
        async_load16(Kh + (size_t)k * DMODEL + (ksl ^ (k & 15)) * 8,
                     &Ks[0][(wave * 8 + i * 4) * 128]);
    }
    #pragma unroll
    for (int i = 0; i < 2; ++i) {
        const int d = dq + i * 16;
        async_load16(Vth + (size_t)d * SEQ + (vsl ^ ((d >> 1) & 3)) * 8,
                     &Vs[0][(wave * 32 + i * 16) * 32]);
    }
    __syncthreads();

    for (int t = 0; t < nT; ++t) {
        const int kb  = t * 32;
        const int buf = t & 1;

        if (t + 1 < nT) {
            const int kb1 = kb + 32;
            #pragma unroll
            for (int i = 0; i < 2; ++i) {
                const int k = kq + i * 4;
                async_load16(Kh + (size_t)(kb1 + k) * DMODEL + (ksl ^ (k & 15)) * 8,
                             &Ks[buf ^ 1][(wave * 8 + i * 4) * 128]);
            }
            #pragma unroll
            for (int i = 0; i < 2; ++i) {
                const int d = dq + i * 16;
                async_load16(Vth + (size_t)d * SEQ + kb1 + (vsl ^ ((d >> 1) & 3)) * 8,
                             &Vs[buf ^ 1][(wave * 32 + i * 16) * 32]);
            }
        }

        if (kb <= q0w + 15) {
            const unsigned short* KsB = Ks[buf];
            const unsigned short* VsB = Vs[buf];

            f32x4 s0 = (f32x4){0.f,0.f,0.f,0.f}, s1 = (f32x4){0.f,0.f,0.f,0.f};
            #pragma unroll
            for (int c = 0; c < 4; ++c) {
                const int slot = (c * 4 + quad) ^ ln15;
                short8 kf0 = *(const short8*)(&KsB[ln15 * 128 + slot * 8]);
                short8 kf1 = *(const short8*)(&KsB[(16 + ln15) * 128 + slot * 8]);
                s0 = __builtin_amdgcn_mfma_f32_16x16x32_bf16(qf[c], kf0, s0, 0, 0, 0);
                s1 = __builtin_amdgcn_mfma_f32_16x16x32_bf16(qf[c], kf1, s1, 0, 0, 0);
            }

            float p0[4], p1[4];
            if (kb + 31 <= q0w) {
                // fully unmasked fast path
                #pragma unroll
                for (int r = 0; r < 4; ++r) {
                    p0[r] = exp2f(fmaf(s0[r], sc2, c0[r]));
                    p1[r] = exp2f(fmaf(s1[r], sc2, c0[r] + slope16));
                    lsum[r] += p0[r] + p1[r];
                }
            } else {
                // diagonal tile: per-element causal mask
                #pragma unroll
                for (int r = 0; r < 4; ++r) {
                    const int qrow = q0w + quad * 4 + r;
                    const int k0i = kb + ln15;
                    const float e0 = exp2f(fmaf(s0[r], sc2, c0[r]));
                    const float e1 = exp2f(fmaf(s1[r], sc2, c0[r] + slope16));
                    p0[r] = (k0i      <= qrow) ? e0 : 0.f;
                    p1[r] = (k0i + 16 <= qrow) ? e1 : 0.f;
                    lsum[r] += p0[r] + p1[r];
                }
            }

            #pragma unroll
            for (int r = 0; r < 4; ++r) {
                Pw[(quad * 4 + r) * ATT_P_STRIDE + ln15]      = f2bf(p0[r]);
                Pw[(quad * 4 + r) * ATT_P_STRIDE + 16 + ln15] = f2bf(p1[r]);
            }
            __builtin_amdgcn_s_waitcnt(0xC07F);   // lgkmcnt(0)
            short8 pf = *(const short8*)(&Pw[ln15 * ATT_P_STRIDE + quad * 8]);

            #pragma unroll
            for (int nt = 0; nt < 8; ++nt) {
                short8 vf = *(const short8*)(
                    &VsB[(nt * 16 + ln15) * 32 + (quad ^ vsw) * 8]);
                acc[nt] = __builtin_amdgcn_mfma_f32_16x16x32_bf16(pf, vf, acc[nt], 0, 0, 0);
            }
        }

        #pragma unroll
        for (int r = 0; r < 4; ++r) c0[r] += slope32;
        __syncthreads();
    }

    #pragma unroll
    for (int r = 0; r < 4; ++r) {
        float l = lsum[r];
        l += __shfl_xor(l, 1, 64);
        l += __shfl_xor(l, 2, 64);
        l += __shfl_xor(l, 4, 64);
        l += __shfl_xor(l, 8, 64);
        const float inv = 1.0f / l;
        const size_t ob = (rowbase + q0w + quad * 4 + r) * DMODEL + hoff;
        #pragma unroll
        for (int nt = 0; nt < 8; ++nt)
            O[ob + nt * 16 + ln15] = f2bf(acc[nt][r] * inv);
    }
}

// ---------------------------------------------------------------------------
extern "C" void kernel_launch(void* const* d_in, const int* in_sizes, int n_in,
                              void* d_out, int out_size, void* d_ws, size_t ws_size,
                              hipStream_t stream)
{
    const float* x  = (const float*)d_in[0];
    const float* wq = (const float*)d_in[1];
    const float* bq = (const float*)d_in[2];
    const float* wk = (const float*)d_in[3];
    const float* bk = (const float*)d_in[4];
    const float* wv = (const float*)d_in[5];
    const float* bv = (const float*)d_in[6];
    const float* wo = (const float*)d_in[7];
    const float* bo = (const float*)d_in[8];
    float* out = (float*)d_out;

    const size_t bufElems = (size_t)MROWS * DMODEL;   // 8.39M
    unsigned short* Qb  = (unsigned short*)d_ws;
    unsigned short* Kb  = Qb + bufElems;
    unsigned short* Vtg = Kb + bufElems;      // V^T: [B*H][HDIM][SEQ]
    unsigned short* xb  = Vtg + bufElems;     // x bf16; later reused as Ob
    unsigned short* Ob  = xb;                 // alias (xb dead after QKV GEMM)
    unsigned short* Wt  = xb + bufElems;      // 3 slots of 2048*2048 bf16

    const dim3 blk(256);

    convert_bf16_kernel<<<dim3((int)(bufElems / 1024)), blk, 0, stream>>>(
        x, xb, (int)bufElems);

    transpose3_bf16_kernel<<<dim3(32, 32, 3), blk, 0, stream>>>(wq, wk, wv, Wt);

    qkv_gemm_kernel<<<dim3(768), dim3(512), 0, stream>>>(
        xb, Wt, bq, bk, bv, Qb, Kb, Vtg);

    // wo -> Wt slot 0 (QKV GEMM has consumed it by stream order)
    transpose_bf16_kernel<<<dim3(32, 32), blk, 0, stream>>>(wo, Wt, DMODEL, DMODEL);

    attn_kernel<<<dim3(1024), blk, 0, stream>>>(Qb, Kb, Vtg, Ob);

    gemm_out256_kernel<<<dim3(256), dim3(512), 0, stream>>>(
        Ob, Wt, bo, out);
}

// Round 4
// 378.887 us; speedup vs baseline: 1.1094x; 1.0306x over previous
//
#include <hip/hip_runtime.h>
#include <hip/hip_bf16.h>
#include <math.h>

// Problem constants (fixed by reference)
#define BATCH 2
#define SEQ   2048
#define DMODEL 2048
#define NHEADS 16
#define HDIM  128
#define MROWS (BATCH * SEQ)   // 4096

typedef __attribute__((ext_vector_type(8))) short short8;
typedef __attribute__((ext_vector_type(8))) unsigned short ushort8;
typedef __attribute__((ext_vector_type(4))) float f32x4;

static __device__ __forceinline__ unsigned short f2bf(float x) {
    __hip_bfloat16 h = __float2bfloat16(x);
    return __builtin_bit_cast(unsigned short, h);
}

static __device__ __forceinline__ void async_load16(const void* g, void* l) {
    __builtin_amdgcn_global_load_lds(
        (const __attribute__((address_space(1))) unsigned int*)g,
        (__attribute__((address_space(3))) unsigned int*)l, 16, 0, 0);
}

// ---------------------------------------------------------------------------
// fp32 -> bf16 elementwise convert (x)
// ---------------------------------------------------------------------------
__global__ __launch_bounds__(256) void convert_bf16_kernel(
    const float* __restrict__ in, unsigned short* __restrict__ out, int n)
{
    const int idx = (blockIdx.x * 256 + threadIdx.x) * 4;
    if (idx < n) {
        const float4 v = *(const float4*)(in + idx);
        ushort4 u;
        u.x = f2bf(v.x); u.y = f2bf(v.y); u.z = f2bf(v.z); u.w = f2bf(v.w);
        *(ushort4*)(out + idx) = u;
    }
}

// ---------------------------------------------------------------------------
// Fused transpose of wq,wk,wv: [K,N] fp32 -> [N,K] bf16 into 3 Wt slots.
// ---------------------------------------------------------------------------
__global__ __launch_bounds__(256) void transpose3_bf16_kernel(
    const float* __restrict__ w0, const float* __restrict__ w1,
    const float* __restrict__ w2, unsigned short* __restrict__ WtAll)
{
    const float* W = blockIdx.z == 0 ? w0 : (blockIdx.z == 1 ? w1 : w2);
    unsigned short* Wt = WtAll + (size_t)blockIdx.z * DMODEL * DMODEL;

    __shared__ float T[64][65];
    const int tid = threadIdx.x;
    const int tr  = tid >> 4;
    const int tc4 = (tid & 15) * 4;
    const int k0 = blockIdx.y * 64;
    const int n0 = blockIdx.x * 64;

    #pragma unroll
    for (int i = 0; i < 4; ++i) {
        const int kr = i * 16 + tr;
        const float4 v = *(const float4*)(W + (size_t)(k0 + kr) * DMODEL + n0 + tc4);
        T[kr][tc4 + 0] = v.x; T[kr][tc4 + 1] = v.y;
        T[kr][tc4 + 2] = v.z; T[kr][tc4 + 3] = v.w;
    }
    __syncthreads();
    #pragma unroll
    for (int i = 0; i < 4; ++i) {
        const int nr = i * 16 + tr;
        ushort4 u;
        u.x = f2bf(T[tc4 + 0][nr]); u.y = f2bf(T[tc4 + 1][nr]);
        u.z = f2bf(T[tc4 + 2][nr]); u.w = f2bf(T[tc4 + 3][nr]);
        *(ushort4*)(Wt + (size_t)(n0 + nr) * DMODEL + k0 + tc4) = u;
    }
}

// single transpose (for wo)
__global__ __launch_bounds__(256) void transpose_bf16_kernel(
    const float* __restrict__ W, unsigned short* __restrict__ Wt, int K, int N)
{
    __shared__ float T[64][65];
    const int tid = threadIdx.x;
    const int tr  = tid >> 4;
    const int tc4 = (tid & 15) * 4;
    const int k0 = blockIdx.y * 64;
    const int n0 = blockIdx.x * 64;

    #pragma unroll
    for (int i = 0; i < 4; ++i) {
        const int kr = i * 16 + tr;
        const float4 v = *(const float4*)(W + (size_t)(k0 + kr) * N + n0 + tc4);
        T[kr][tc4 + 0] = v.x; T[kr][tc4 + 1] = v.y;
        T[kr][tc4 + 2] = v.z; T[kr][tc4 + 3] = v.w;
    }
    __syncthreads();
    #pragma unroll
    for (int i = 0; i < 4; ++i) {
        const int nr = i * 16 + tr;
        ushort4 u;
        u.x = f2bf(T[tc4 + 0][nr]); u.y = f2bf(T[tc4 + 1][nr]);
        u.z = f2bf(T[tc4 + 2][nr]); u.w = f2bf(T[tc4 + 3][nr]);
        *(ushort4*)(Wt + (size_t)(n0 + nr) * K + k0 + tc4) = u;
    }
}

// ---------------------------------------------------------------------------
// Fused QKV GEMM — 256x192 tile, BK=64, 8 waves (4M x 2N, wave-tile 64x96).
// Grid 16 by x 32 bx = 512 blocks = EXACTLY 2 rounds on 256 CUs (no tail).
// Tile geometry chosen to cut LDS:MFMA ratio vs round-2's 128x256:
//   per K-tile: MFMA 1545 cy, frag reads 20/wave*8 = 160 KB ~= 1920 cy
//   (was 1030 cy MFMA vs 1540 cy reads -> ceiling 50%; now ~65%).
// 2-phase counted-vmcnt schedule (proven r2): ph1 reads all 20 frags + MFMA
// mt0-1; ph2 stages all 7 units of tile t+2 + MFMA mt2-3; vmcnt(7) once per
// K-tile (14 in flight steady-state, retires exactly tile t+1's 7 units).
// T2 XOR-granule swizzle both-sides (0 conflicts measured r1-r3).
// N=192 tiles cross the Q/K/V 2048-col boundaries; every 16-col fragment
// stays inside one segment (16 | 2048), so widx routing is per-fragment in
// the epilogue, wave-uniform (no divergence). B addressed as [6144][2048].
// XCD chunk: each XCD owns 2 M-bands (2 MB A, L2-resident), streams B.
// ---------------------------------------------------------------------------
__global__ __launch_bounds__(512, 2) void qkv_gemm192_kernel(
    const unsigned short* __restrict__ A, const unsigned short* __restrict__ WtAll,
    const float* __restrict__ bq, const float* __restrict__ bk,
    const float* __restrict__ bv,
    unsigned short* __restrict__ Qb, unsigned short* __restrict__ Kb,
    unsigned short* __restrict__ Vt)
{
    constexpr int K  = DMODEL;   // 2048
    constexpr int NT = K / 64;   // 32 K-tiles

    __shared__ __align__(16) unsigned short As[2][256 * 64];   // 32 KB each
    __shared__ __align__(16) unsigned short Bs[2][192 * 64];   // 24 KB each

    const int tid  = threadIdx.x;
    const int lane = tid & 63;
    const int wave = tid >> 6;      // 0..7
    const int ln15 = lane & 15;
    const int quad = lane >> 4;
    const int wr   = wave >> 1;     // 0..3  (M quarter, 64 rows)
    const int wc   = wave & 1;      // 0..1  (N half, 96 cols)

    // XCD-aware bijective swizzle: nwg=512, 64 per XCD; bx fastest within XCD
    const int bid = (blockIdx.x & 7) * 64 + (blockIdx.x >> 3);
    const int bx  = bid & 31;              // 0..31  N tile
    const int by  = bid >> 5;              // 0..15  M tile
    const int bm  = by * 256;
    const int bn  = bx * 192;              // 0..5952

    // ---- staging: thread -> (row sr within 64-row unit, swizzled src granule)
    const int sr = tid >> 3;                 // 0..63
    const int sg = (tid & 7) ^ (sr & 7);     // XOR swizzle (involution)
    const unsigned short* Ag = A     + (size_t)(bm + sr) * K + sg * 8;
    const unsigned short* Bg = WtAll + (size_t)(bn + sr) * K + sg * 8;

    // ---- ds_read offsets (ushort units); physical granule = logical ^ (row&7)
    const int swz0 = ((0 + quad) ^ (ln15 & 7)) * 8;   // ks=0
    const int swz1 = ((4 + quad) ^ (ln15 & 7)) * 8;   // ks=1
    const int arow = (wr * 64 + ln15) * 64;           // + mp*1024
    const int brow = (wc * 96 + ln15) * 64;           // + np*1024

#define STAGE_A(c, q, k0) async_load16(Ag + (size_t)(q) * 64 * K + (k0), \
                                       &As[c][(q) * 4096 + wave * 512])
#define STAGE_B(c, q, k0) async_load16(Bg + (size_t)(q) * 64 * K + (k0), \
                                       &Bs[c][(q) * 4096 + wave * 512])

    f32x4 acc[4][6];
    #pragma unroll
    for (int i = 0; i < 4; ++i)
        #pragma unroll
        for (int j = 0; j < 6; ++j) acc[i][j] = (f32x4){0.f, 0.f, 0.f, 0.f};

    // ---- prologue: tiles 0 and 1 fully staged (7 units each) ----
    STAGE_A(0, 0, 0); STAGE_A(0, 1, 0); STAGE_A(0, 2, 0); STAGE_A(0, 3, 0);
    STAGE_B(0, 0, 0); STAGE_B(0, 1, 0); STAGE_B(0, 2, 0);
    STAGE_A(1, 0, 64); STAGE_A(1, 1, 64); STAGE_A(1, 2, 64); STAGE_A(1, 3, 64);
    STAGE_B(1, 0, 64); STAGE_B(1, 1, 64); STAGE_B(1, 2, 64);
    asm volatile("s_waitcnt vmcnt(7)" ::: "memory");   // tile 0 landed
    __builtin_amdgcn_s_barrier();

    short8 af[4][2];
    short8 bfr[6][2];

    #pragma unroll 2
    for (int t = 0; t < NT; ++t) {
        const int c  = t & 1;
        const int k2 = (t + 2) * 64;
        const unsigned short* Ac = As[c];
        const unsigned short* Bc = Bs[c];

        // ---- phase 1: read ALL 20 frags; MFMA mt0-1 ----
        #pragma unroll
        for (int np = 0; np < 6; ++np) {
            bfr[np][0] = *(const short8*)(Bc + brow + np * 1024 + swz0);
            bfr[np][1] = *(const short8*)(Bc + brow + np * 1024 + swz1);
        }
        #pragma unroll
        for (int mp = 0; mp < 4; ++mp) {
            af[mp][0] = *(const short8*)(Ac + arow + mp * 1024 + swz0);
            af[mp][1] = *(const short8*)(Ac + arow + mp * 1024 + swz1);
        }
        __builtin_amdgcn_s_barrier();
        asm volatile("s_waitcnt lgkmcnt(0)" ::: "memory");
        __builtin_amdgcn_sched_barrier(0);
        __builtin_amdgcn_s_setprio(1);
        #pragma unroll
        for (int ks = 0; ks < 2; ++ks)
            #pragma unroll
            for (int mt = 0; mt < 2; ++mt)
                #pragma unroll
                for (int nt = 0; nt < 6; ++nt)
                    acc[mt][nt] = __builtin_amdgcn_mfma_f32_16x16x32_bf16(
                        af[mt][ks], bfr[nt][ks], acc[mt][nt], 0, 0, 0);
        __builtin_amdgcn_s_setprio(0);
        __builtin_amdgcn_s_barrier();

        // ---- phase 2: stage all 7 units of tile t+2; MFMA mt2-3 ----
        if (t + 2 < NT) {
            STAGE_A(c, 0, k2); STAGE_A(c, 1, k2);
            STAGE_A(c, 2, k2); STAGE_A(c, 3, k2);
            STAGE_B(c, 0, k2); STAGE_B(c, 1, k2); STAGE_B(c, 2, k2);
        }
        __builtin_amdgcn_s_setprio(1);
        #pragma unroll
        for (int ks = 0; ks < 2; ++ks)
            #pragma unroll
            for (int mt = 2; mt < 4; ++mt)
                #pragma unroll
                for (int nt = 0; nt < 6; ++nt)
                    acc[mt][nt] = __builtin_amdgcn_mfma_f32_16x16x32_bf16(
                        af[mt][ks], bfr[nt][ks], acc[mt][nt], 0, 0, 0);
        __builtin_amdgcn_s_setprio(0);
        if (t + 2 < NT) { asm volatile("s_waitcnt vmcnt(7)" ::: "memory"); }
        else            { asm volatile("s_waitcnt vmcnt(0)" ::: "memory"); }
        __builtin_amdgcn_s_barrier();
    }

#undef STAGE_A
#undef STAGE_B

    // ---- epilogue: per-fragment Q/K/V routing (wave-uniform per np) ----
    #pragma unroll
    for (int mp = 0; mp < 4; ++mp) {
        const int m0 = bm + wr * 64 + mp * 16 + quad * 4;
        #pragma unroll
        for (int np = 0; np < 6; ++np) {
            const int col  = bn + wc * 96 + np * 16 + ln15;
            const int widx = col >> 11;            // 0=Q 1=K 2=V
            const int lcol = col & 2047;
            const float bvv = widx == 0 ? bq[lcol] : (widx == 1 ? bk[lcol] : bv[lcol]);
            if (widx == 2) {
                const int bb = m0 >> 11;
                const int s0 = m0 & 2047;
                ushort4 pk;
                pk.x = f2bf(acc[mp][np][0] + bvv);
                pk.y = f2bf(acc[mp][np][1] + bvv);
                pk.z = f2bf(acc[mp][np][2] + bvv);
                pk.w = f2bf(acc[mp][np][3] + bvv);
                *(ushort4*)(Vt + ((size_t)(bb * 16 + (lcol >> 7)) * 128 + (lcol & 127)) * SEQ + s0) = pk;
            } else {
                unsigned short* dst = widx ? Kb : Qb;
                #pragma unroll
                for (int r = 0; r < 4; ++r)
                    dst[(size_t)(m0 + r) * DMODEL + lcol] = f2bf(acc[mp][np][r] + bvv);
            }
        }
    }
}

// ---------------------------------------------------------------------------
// Out-projection GEMM — 128x256 BK=64 2-phase counted-vmcnt structure,
// fp32 epilogue. 256 blocks = exactly 1 round. Unchanged from round 3.
// ---------------------------------------------------------------------------
__global__ __launch_bounds__(512, 2) void gemm_out256_kernel(
    const unsigned short* __restrict__ A, const unsigned short* __restrict__ Bt,
    const float* __restrict__ bias, float* __restrict__ C)
{
    constexpr int K  = DMODEL;   // 2048
    constexpr int N  = DMODEL;   // 2048
    constexpr int NT = K / 64;   // 32 K-tiles

    __shared__ __align__(16) unsigned short As[2][128 * 64];   // 32 KB
    __shared__ __align__(16) unsigned short Bs[2][256 * 64];   // 64 KB

    const int tid  = threadIdx.x;
    const int lane = tid & 63;
    const int wave = tid >> 6;      // 0..7
    const int ln15 = lane & 15;
    const int quad = lane >> 4;
    const int wr   = wave >> 2;     // 0..1  (M half)
    const int wc   = wave & 3;      // 0..3  (N quarter)

    const int bx = blockIdx.x & 7;         // N tile (XCD-pinned)
    const int by = blockIdx.x >> 3;        // M tile
    const int bm = by * 128;
    const int bn = bx * 256;

    const int sr = tid >> 3;
    const int sg = (tid & 7) ^ (sr & 7);
    const unsigned short* Ag = A  + (size_t)(bm + sr) * K + sg * 8;
    const unsigned short* Bg = Bt + (size_t)(bn + sr) * K + sg * 8;

    const int swz0 = ((0 + quad) ^ (ln15 & 7)) * 8;
    const int swz1 = ((4 + quad) ^ (ln15 & 7)) * 8;
    const int arow = (wr * 64 + ln15) * 64;
    const int brow = (wc * 64 + ln15) * 64;

#define STAGE_A(c, q, k0) async_load16(Ag + (size_t)(q) * 64 * K + (k0), \
                                       &As[c][(q) * 4096 + wave * 512])
#define STAGE_B(c, q, k0) async_load16(Bg + (size_t)(q) * 64 * K + (k0), \
                                       &Bs[c][(q) * 4096 + wave * 512])

    f32x4 acc[4][4];
    #pragma unroll
    for (int i = 0; i < 4; ++i)
        #pragma unroll
        for (int j = 0; j < 4; ++j) acc[i][j] = (f32x4){0.f, 0.f, 0.f, 0.f};

    STAGE_A(0, 0, 0); STAGE_A(0, 1, 0);
    STAGE_B(0, 0, 0); STAGE_B(0, 1, 0); STAGE_B(0, 2, 0); STAGE_B(0, 3, 0);
    STAGE_A(1, 0, 64); STAGE_A(1, 1, 64);
    STAGE_B(1, 0, 64); STAGE_B(1, 1, 64); STAGE_B(1, 2, 64); STAGE_B(1, 3, 64);
    asm volatile("s_waitcnt vmcnt(6)" ::: "memory");
    __builtin_amdgcn_s_barrier();

    short8 af[4][2];
    short8 bfr[4][2];

    #pragma unroll 2
    for (int t = 0; t < NT; ++t) {
        const int c  = t & 1;
        const int k2 = (t + 2) * 64;
        const unsigned short* Ac = As[c];
        const unsigned short* Bc = Bs[c];

        #pragma unroll
        for (int np = 0; np < 4; ++np) {
            bfr[np][0] = *(const short8*)(Bc + brow + np * 1024 + swz0);
            bfr[np][1] = *(const short8*)(Bc + brow + np * 1024 + swz1);
        }
        #pragma unroll
        for (int mp = 0; mp < 4; ++mp) {
            af[mp][0] = *(const short8*)(Ac + arow + mp * 1024 + swz0);
            af[mp][1] = *(const short8*)(Ac + arow + mp * 1024 + swz1);
        }
        __builtin_amdgcn_s_barrier();
        asm volatile("s_waitcnt lgkmcnt(0)" ::: "memory");
        __builtin_amdgcn_sched_barrier(0);
        __builtin_amdgcn_s_setprio(1);
        #pragma unroll
        for (int ks = 0; ks < 2; ++ks)
            #pragma unroll
            for (int mt = 0; mt < 2; ++mt)
                #pragma unroll
                for (int nt = 0; nt < 4; ++nt)
                    acc[mt][nt] = __builtin_amdgcn_mfma_f32_16x16x32_bf16(
                        af[mt][ks], bfr[nt][ks], acc[mt][nt], 0, 0, 0);
        __builtin_amdgcn_s_setprio(0);
        __builtin_amdgcn_s_barrier();

        if (t + 2 < NT) {
            STAGE_A(c, 0, k2); STAGE_A(c, 1, k2);
            STAGE_B(c, 0, k2); STAGE_B(c, 1, k2);
            STAGE_B(c, 2, k2); STAGE_B(c, 3, k2);
        }
        __builtin_amdgcn_s_setprio(1);
        #pragma unroll
        for (int ks = 0; ks < 2; ++ks)
            #pragma unroll
            for (int mt = 2; mt < 4; ++mt)
                #pragma unroll
                for (int nt = 0; nt < 4; ++nt)
                    acc[mt][nt] = __builtin_amdgcn_mfma_f32_16x16x32_bf16(
                        af[mt][ks], bfr[nt][ks], acc[mt][nt], 0, 0, 0);
        __builtin_amdgcn_s_setprio(0);
        if (t + 2 < NT) { asm volatile("s_waitcnt vmcnt(6)" ::: "memory"); }
        else            { asm volatile("s_waitcnt vmcnt(0)" ::: "memory"); }
        __builtin_amdgcn_s_barrier();
    }

#undef STAGE_A
#undef STAGE_B

    #pragma unroll
    for (int mp = 0; mp < 4; ++mp)
        #pragma unroll
        for (int r = 0; r < 4; ++r) {
            const int row = bm + wr * 64 + mp * 16 + quad * 4 + r;
            #pragma unroll
            for (int np = 0; np < 4; ++np) {
                const int col = bn + wc * 64 + np * 16 + ln15;
                C[(size_t)row * N + col] = acc[mp][np][r] + bias[col];
            }
        }
}

// ---------------------------------------------------------------------------
// MFMA flash attention — LDS-staged, double-buffered, fast-path/diagonal
// split, XCD-pinned. 1024 single-qblk blocks, 4 blocks/CU. Unchanged from
// round 3 (isolating the qkv change this round).
// ---------------------------------------------------------------------------
#define ATT_P_STRIDE 40

__global__ __launch_bounds__(256, 4) void attn_kernel(
    const unsigned short* __restrict__ Qb, const unsigned short* __restrict__ Kb,
    const unsigned short* __restrict__ Vt,   // [B*H][HDIM][SEQ]
    unsigned short* __restrict__ O)
{
    __shared__ __align__(16) unsigned short Ks[2][32 * 128];
    __shared__ __align__(16) unsigned short Vs[2][128 * 32];
    __shared__ __align__(16) unsigned short Pl[4 * 16 * ATT_P_STRIDE];

    const int tid  = threadIdx.x;
    const int lane = tid & 63;
    const int wave = tid >> 6;
    const int ln15 = lane & 15;
    const int quad = lane >> 4;

    // XCD pinning: id = j*32 + g, g = head-group (b,h); long qblks first
    const int g = blockIdx.x & 31;
    const int qblk = 31 - (blockIdx.x >> 5);   // 0..31, descending issue
    const int h = g & 15;
    const int b = g >> 4;

    const size_t rowbase = (size_t)b * SEQ;
    const size_t hoff    = (size_t)h * HDIM;
    const unsigned short* Kh  = Kb + rowbase * DMODEL + hoff;
    const unsigned short* Vth = Vt + (size_t)(b * NHEADS + h) * HDIM * SEQ;

    const float sc2     = 0.08838834764831845f * 1.4426950408889634f;
    const float slope2  = exp2f(-0.5f * (float)(h + 1)) * 1.4426950408889634f;
    const float slope16 = slope2 * 16.0f;
    const float slope32 = slope2 * 32.0f;

    // staging lane roles
    const int kq  = wave * 8 + (lane >> 4);
    const int ksl = lane & 15;
    const int dq  = wave * 32 + (lane >> 2);
    const int vsl = lane & 3;
    const int vsw = (ln15 >> 1) & 3;

    unsigned short* Pw = &Pl[wave * 16 * ATT_P_STRIDE];

    const int q0w  = qblk * 64 + wave * 16;
    const int nT   = 2 * qblk + 2;

    short8 qf[4];
    {
        const unsigned short* qp =
            Qb + (rowbase + q0w + ln15) * DMODEL + hoff + quad * 8;
        qf[0] = *(const short8*)(qp);
        qf[1] = *(const short8*)(qp + 32);
        qf[2] = *(const short8*)(qp + 64);
        qf[3] = *(const short8*)(qp + 96);
    }

    f32x4 acc[8];
    #pragma unroll
    for (int nt = 0; nt < 8; ++nt) acc[nt] = (f32x4){0.f, 0.f, 0.f, 0.f};
    float lsum[4] = {0.f, 0.f, 0.f, 0.f};

    // incremental ALiBi bias: c0[r] = slope2*(kb+ln15 - (q0w+quad*4+r))
    float c0[4];
    {
        const float base = slope2 * (float)(ln15 - q0w - quad * 4);
        #pragma unroll
        for (int r = 0; r < 4; ++r) c0[r] = base - slope2 * (float)r;
    }

    // ---- stage tile 0 into buffer 0 ----
    #pragma unroll
    for (int i = 0; i < 2; ++i) {
        const int k = kq + i * 4;
        async_load16(Kh + (size_t)k * DMODEL + (ksl ^ (k & 15)) * 8,
                     &Ks[0][(wave * 8 + i * 4) * 128]);
    }
    #pragma unroll
    for (int i = 0; i < 2; ++i) {
        const int d = dq + i * 16;
        async_load16(Vth + (size_t)d * SEQ + (vsl ^ ((d >> 1) & 3)) * 8,
                     &Vs[0][(wave * 32 + i * 16) * 32]);
    }
    __syncthreads();

    for (int t = 0; t < nT; ++t) {
        const int kb  = t * 32;
        const int buf = t & 1;

        if (t + 1 < nT) {
            const int kb1 = kb + 32;
            #pragma unroll
            for (int i = 0; i < 2; ++i) {
                const int k = kq + i * 4;
                async_load16(Kh + (size_t)(kb1 + k) * DMODEL + (ksl ^ (k & 15)) * 8,
                             &Ks[buf ^ 1][(wave * 8 + i * 4) * 128]);
            }
            #pragma unroll
            for (int i = 0; i < 2; ++i) {
                const int d = dq + i * 16;
                async_load16(Vth + (size_t)d * SEQ + kb1 + (vsl ^ ((d >> 1) & 3)) * 8,
                             &Vs[buf ^ 1][(wave * 32 + i * 16) * 32]);
            }
        }

        if (kb <= q0w + 15) {
            const unsigned short* KsB = Ks[buf];
            const unsigned short* VsB = Vs[buf];

            f32x4 s0 = (f32x4){0.f,0.f,0.f,0.f}, s1 = (f32x4){0.f,0.f,0.f,0.f};
            #pragma unroll
            for (int c = 0; c < 4; ++c) {
                const int slot = (c * 4 + quad) ^ ln15;
                short8 kf0 = *(const short8*)(&KsB[ln15 * 128 + slot * 8]);
                short8 kf1 = *(const short8*)(&KsB[(16 + ln15) * 128 + slot * 8]);
                s0 = __builtin_amdgcn_mfma_f32_16x16x32_bf16(qf[c], kf0, s0, 0, 0, 0);
                s1 = __builtin_amdgcn_mfma_f32_16x16x32_bf16(qf[c], kf1, s1, 0, 0, 0);
            }

            float p0[4], p1[4];
            if (kb + 31 <= q0w) {
                // fully unmasked fast path
                #pragma unroll
                for (int r = 0; r < 4; ++r) {
                    p0[r] = exp2f(fmaf(s0[r], sc2, c0[r]));
                    p1[r] = exp2f(fmaf(s1[r], sc2, c0[r] + slope16));
                    lsum[r] += p0[r] + p1[r];
                }
            } else {
                // diagonal tile: per-element causal mask
                #pragma unroll
                for (int r = 0; r < 4; ++r) {
                    const int qrow = q0w + quad * 4 + r;
                    const int k0i = kb + ln15;
                    const float e0 = exp2f(fmaf(s0[r], sc2, c0[r]));
                    const float e1 = exp2f(fmaf(s1[r], sc2, c0[r] + slope16));
                    p0[r] = (k0i      <= qrow) ? e0 : 0.f;
                    p1[r] = (k0i + 16 <= qrow) ? e1 : 0.f;
                    lsum[r] += p0[r] + p1[r];
                }
            }

            #pragma unroll
            for (int r = 0; r < 4; ++r) {
                Pw[(quad * 4 + r) * ATT_P_STRIDE + ln15]      = f2bf(p0[r]);
                Pw[(quad * 4 + r) * ATT_P_STRIDE + 16 + ln15] = f2bf(p1[r]);
            }
            __builtin_amdgcn_s_waitcnt(0xC07F);   // lgkmcnt(0)
            short8 pf = *(const short8*)(&Pw[ln15 * ATT_P_STRIDE + quad * 8]);

            #pragma unroll
            for (int nt = 0; nt < 8; ++nt) {
                short8 vf = *(const short8*)(
                    &VsB[(nt * 16 + ln15) * 32 + (quad ^ vsw) * 8]);
                acc[nt] = __builtin_amdgcn_mfma_f32_16x16x32_bf16(pf, vf, acc[nt], 0, 0, 0);
            }
        }

        #pragma unroll
        for (int r = 0; r < 4; ++r) c0[r] += slope32;
        __syncthreads();
    }

    #pragma unroll
    for (int r = 0; r < 4; ++r) {
        float l = lsum[r];
        l += __shfl_xor(l, 1, 64);
        l += __shfl_xor(l, 2, 64);
        l += __shfl_xor(l, 4, 64);
        l += __shfl_xor(l, 8, 64);
        const float inv = 1.0f / l;
        const size_t ob = (rowbase + q0w + quad * 4 + r) * DMODEL + hoff;
        #pragma unroll
        for (int nt = 0; nt < 8; ++nt)
            O[ob + nt * 16 + ln15] = f2bf(acc[nt][r] * inv);
    }
}

// ---------------------------------------------------------------------------
extern "C" void kernel_launch(void* const* d_in, const int* in_sizes, int n_in,
                              void* d_out, int out_size, void* d_ws, size_t ws_size,
                              hipStream_t stream)
{
    const float* x  = (const float*)d_in[0];
    const float* wq = (const float*)d_in[1];
    const float* bq = (const float*)d_in[2];
    const float* wk = (const float*)d_in[3];
    const float* bk = (const float*)d_in[4];
    const float* wv = (const float*)d_in[5];
    const float* bv = (const float*)d_in[6];
    const float* wo = (const float*)d_in[7];
    const float* bo = (const float*)d_in[8];
    float* out = (float*)d_out;

    const size_t bufElems = (size_t)MROWS * DMODEL;   // 8.39M
    unsigned short* Qb  = (unsigned short*)d_ws;
    unsigned short* Kb  = Qb + bufElems;
    unsigned short* Vtg = Kb + bufElems;      // V^T: [B*H][HDIM][SEQ]
    unsigned short* xb  = Vtg + bufElems;     // x bf16; later reused as Ob
    unsigned short* Ob  = xb;                 // alias (xb dead after QKV GEMM)
    unsigned short* Wt  = xb + bufElems;      // 3 slots of 2048*2048 bf16

    const dim3 blk(256);

    convert_bf16_kernel<<<dim3((int)(bufElems / 1024)), blk, 0, stream>>>(
        x, xb, (int)bufElems);

    transpose3_bf16_kernel<<<dim3(32, 32, 3), blk, 0, stream>>>(wq, wk, wv, Wt);

    qkv_gemm192_kernel<<<dim3(512), dim3(512), 0, stream>>>(
        xb, Wt, bq, bk, bv, Qb, Kb, Vtg);

    // wo -> Wt slot 0 (QKV GEMM has consumed it by stream order)
    transpose_bf16_kernel<<<dim3(32, 32), blk, 0, stream>>>(wo, Wt, DMODEL, DMODEL);

    attn_kernel<<<dim3(1024), blk, 0, stream>>>(Qb, Kb, Vtg, Ob);

    gemm_out256_kernel<<<dim3(256), dim3(512), 0, stream>>>(
        Ob, Wt, bo, out);
}

// Round 5
// 371.613 us; speedup vs baseline: 1.1312x; 1.0196x over previous
//
#include <hip/hip_runtime.h>
#include <hip/hip_bf16.h>
#include <math.h>

// Problem constants (fixed by reference)
#define BATCH 2
#define SEQ   2048
#define DMODEL 2048
#define NHEADS 16
#define HDIM  128
#define MROWS (BATCH * SEQ)   // 4096

typedef __attribute__((ext_vector_type(8))) short short8;
typedef __attribute__((ext_vector_type(8))) unsigned short ushort8;
typedef __attribute__((ext_vector_type(4))) float f32x4;

static __device__ __forceinline__ unsigned short f2bf(float x) {
    __hip_bfloat16 h = __float2bfloat16(x);
    return __builtin_bit_cast(unsigned short, h);
}

static __device__ __forceinline__ void async_load16(const void* g, void* l) {
    __builtin_amdgcn_global_load_lds(
        (const __attribute__((address_space(1))) unsigned int*)g,
        (__attribute__((address_space(3))) unsigned int*)l, 16, 0, 0);
}

// ---------------------------------------------------------------------------
// fp32 -> bf16 elementwise convert (x)
// ---------------------------------------------------------------------------
__global__ __launch_bounds__(256) void convert_bf16_kernel(
    const float* __restrict__ in, unsigned short* __restrict__ out, int n)
{
    const int idx = (blockIdx.x * 256 + threadIdx.x) * 4;
    if (idx < n) {
        const float4 v = *(const float4*)(in + idx);
        ushort4 u;
        u.x = f2bf(v.x); u.y = f2bf(v.y); u.z = f2bf(v.z); u.w = f2bf(v.w);
        *(ushort4*)(out + idx) = u;
    }
}

// ---------------------------------------------------------------------------
// Fused transpose of wq,wk,wv: [K,N] fp32 -> [N,K] bf16 into 3 Wt slots.
// ---------------------------------------------------------------------------
__global__ __launch_bounds__(256) void transpose3_bf16_kernel(
    const float* __restrict__ w0, const float* __restrict__ w1,
    const float* __restrict__ w2, unsigned short* __restrict__ WtAll)
{
    const float* W = blockIdx.z == 0 ? w0 : (blockIdx.z == 1 ? w1 : w2);
    unsigned short* Wt = WtAll + (size_t)blockIdx.z * DMODEL * DMODEL;

    __shared__ float T[64][65];
    const int tid = threadIdx.x;
    const int tr  = tid >> 4;
    const int tc4 = (tid & 15) * 4;
    const int k0 = blockIdx.y * 64;
    const int n0 = blockIdx.x * 64;

    #pragma unroll
    for (int i = 0; i < 4; ++i) {
        const int kr = i * 16 + tr;
        const float4 v = *(const float4*)(W + (size_t)(k0 + kr) * DMODEL + n0 + tc4);
        T[kr][tc4 + 0] = v.x; T[kr][tc4 + 1] = v.y;
        T[kr][tc4 + 2] = v.z; T[kr][tc4 + 3] = v.w;
    }
    __syncthreads();
    #pragma unroll
    for (int i = 0; i < 4; ++i) {
        const int nr = i * 16 + tr;
        ushort4 u;
        u.x = f2bf(T[tc4 + 0][nr]); u.y = f2bf(T[tc4 + 1][nr]);
        u.z = f2bf(T[tc4 + 2][nr]); u.w = f2bf(T[tc4 + 3][nr]);
        *(ushort4*)(Wt + (size_t)(n0 + nr) * DMODEL + k0 + tc4) = u;
    }
}

// single transpose (for wo)
__global__ __launch_bounds__(256) void transpose_bf16_kernel(
    const float* __restrict__ W, unsigned short* __restrict__ Wt, int K, int N)
{
    __shared__ float T[64][65];
    const int tid = threadIdx.x;
    const int tr  = tid >> 4;
    const int tc4 = (tid & 15) * 4;
    const int k0 = blockIdx.y * 64;
    const int n0 = blockIdx.x * 64;

    #pragma unroll
    for (int i = 0; i < 4; ++i) {
        const int kr = i * 16 + tr;
        const float4 v = *(const float4*)(W + (size_t)(k0 + kr) * N + n0 + tc4);
        T[kr][tc4 + 0] = v.x; T[kr][tc4 + 1] = v.y;
        T[kr][tc4 + 2] = v.z; T[kr][tc4 + 3] = v.w;
    }
    __syncthreads();
    #pragma unroll
    for (int i = 0; i < 4; ++i) {
        const int nr = i * 16 + tr;
        ushort4 u;
        u.x = f2bf(T[tc4 + 0][nr]); u.y = f2bf(T[tc4 + 1][nr]);
        u.z = f2bf(T[tc4 + 2][nr]); u.w = f2bf(T[tc4 + 3][nr]);
        *(ushort4*)(Wt + (size_t)(n0 + nr) * K + k0 + tc4) = u;
    }
}

// ---------------------------------------------------------------------------
// Fused QKV GEMM — 128x128 tile, BK=64, 256 threads (4 waves, 2Mx2N,
// wave-tile 64x64). LDS = 64 KB -> 2 BLOCKS/CU (the r1-r4 configs all ran
// 1 block/CU; per-tile the lockstep 2-phase serializes LDS-read bursts vs
// MFMA bursts, and with one resident block nothing fills the gaps — all
// landed at 29-33% MfmaUtil regardless of tile shape. Two resident blocks
// interleave phases (m97/m114 mechanism) -> target ~45-50%).
// Grid 48bx x 32by = 1536 = exactly 6 rounds. 2-phase counted-vmcnt
// schedule (proven r2-r4): ph1 reads all 16 frags + MFMA mt0-1; ph2 stages
// all 8 units of tile t+2 + MFMA mt2-3; vmcnt(8) once per K-tile.
// T2 XOR-granule swizzle both-sides (0 conflicts measured r1-r4).
// Per-XCD ordering by-inner: 4 concurrent same-bx blocks share each B-tile
// (L2 reuse), A-band 4x128 rows = 2 MB L2-resident per XCD.
// ---------------------------------------------------------------------------
__global__ __launch_bounds__(256, 2) void qkv_gemm128_kernel(
    const unsigned short* __restrict__ A, const unsigned short* __restrict__ WtAll,
    const float* __restrict__ bq, const float* __restrict__ bk,
    const float* __restrict__ bv,
    unsigned short* __restrict__ Qb, unsigned short* __restrict__ Kb,
    unsigned short* __restrict__ Vt)
{
    constexpr int K  = DMODEL;   // 2048
    constexpr int NT = K / 64;   // 32 K-tiles

    __shared__ __align__(16) unsigned short As[2][128 * 64];   // 16 KB each
    __shared__ __align__(16) unsigned short Bs[2][128 * 64];   // 16 KB each

    const int tid  = threadIdx.x;
    const int lane = tid & 63;
    const int wave = tid >> 6;      // 0..3
    const int ln15 = lane & 15;
    const int quad = lane >> 4;
    const int wr   = wave >> 1;     // 0..1  (M half)
    const int wc   = wave & 1;      // 0..1  (N half)

    // XCD chunking: 1536 blocks, 192/XCD; by-inner so 4 concurrent blocks
    // share a B-tile; XCD k owns by 4k..4k+3 (A band 2 MB, L2-resident).
    const int xcd = blockIdx.x & 7;
    const int loc = blockIdx.x >> 3;       // 0..191
    const int bx  = loc >> 2;              // 0..47  N tile
    const int by  = xcd * 4 + (loc & 3);   // 0..31  M tile
    const int bm  = by * 128;
    const int bn  = bx * 128;              // 0..6016
    const int widx = bn >> 11;             // 0=Q 1=K 2=V
    const int bnl  = bn & 2047;

    const float* bias = widx == 0 ? bq : (widx == 1 ? bk : bv);

    // ---- staging: thread -> (row sr within 32-row unit, swizzled granule) ----
    const int sr = tid >> 3;                 // 0..31
    const int sg = (tid & 7) ^ (sr & 7);     // XOR swizzle (involution)
    const unsigned short* Ag = A     + (size_t)(bm + sr) * K + sg * 8;
    const unsigned short* Bg = WtAll + (size_t)(bn + sr) * K + sg * 8;

    // ---- ds_read offsets (ushort units); physical granule = logical ^ (row&7)
    const int swz0 = ((0 + quad) ^ (ln15 & 7)) * 8;   // ks=0
    const int swz1 = ((4 + quad) ^ (ln15 & 7)) * 8;   // ks=1
    const int arow = (wr * 64 + ln15) * 64;           // + mp*1024
    const int brow = (wc * 64 + ln15) * 64;           // + np*1024

#define STAGE_A(c, q, k0) async_load16(Ag + (size_t)(q) * 32 * K + (k0), \
                                       &As[c][(q) * 2048 + wave * 512])
#define STAGE_B(c, q, k0) async_load16(Bg + (size_t)(q) * 32 * K + (k0), \
                                       &Bs[c][(q) * 2048 + wave * 512])

    f32x4 acc[4][4];
    #pragma unroll
    for (int i = 0; i < 4; ++i)
        #pragma unroll
        for (int j = 0; j < 4; ++j) acc[i][j] = (f32x4){0.f, 0.f, 0.f, 0.f};

    // ---- prologue: tiles 0 and 1 fully staged (8 units each) ----
    STAGE_A(0, 0, 0); STAGE_A(0, 1, 0); STAGE_A(0, 2, 0); STAGE_A(0, 3, 0);
    STAGE_B(0, 0, 0); STAGE_B(0, 1, 0); STAGE_B(0, 2, 0); STAGE_B(0, 3, 0);
    STAGE_A(1, 0, 64); STAGE_A(1, 1, 64); STAGE_A(1, 2, 64); STAGE_A(1, 3, 64);
    STAGE_B(1, 0, 64); STAGE_B(1, 1, 64); STAGE_B(1, 2, 64); STAGE_B(1, 3, 64);
    asm volatile("s_waitcnt vmcnt(8)" ::: "memory");   // tile 0 landed
    __builtin_amdgcn_s_barrier();

    short8 af[4][2];
    short8 bfr[4][2];

    #pragma unroll 2
    for (int t = 0; t < NT; ++t) {
        const int c  = t & 1;
        const int k2 = (t + 2) * 64;
        const unsigned short* Ac = As[c];
        const unsigned short* Bc = Bs[c];

        // ---- phase 1: read ALL 16 frags; MFMA mt0-1 ----
        #pragma unroll
        for (int np = 0; np < 4; ++np) {
            bfr[np][0] = *(const short8*)(Bc + brow + np * 1024 + swz0);
            bfr[np][1] = *(const short8*)(Bc + brow + np * 1024 + swz1);
        }
        #pragma unroll
        for (int mp = 0; mp < 4; ++mp) {
            af[mp][0] = *(const short8*)(Ac + arow + mp * 1024 + swz0);
            af[mp][1] = *(const short8*)(Ac + arow + mp * 1024 + swz1);
        }
        __builtin_amdgcn_s_barrier();
        asm volatile("s_waitcnt lgkmcnt(0)" ::: "memory");
        __builtin_amdgcn_sched_barrier(0);
        __builtin_amdgcn_s_setprio(1);
        #pragma unroll
        for (int ks = 0; ks < 2; ++ks)
            #pragma unroll
            for (int mt = 0; mt < 2; ++mt)
                #pragma unroll
                for (int nt = 0; nt < 4; ++nt)
                    acc[mt][nt] = __builtin_amdgcn_mfma_f32_16x16x32_bf16(
                        af[mt][ks], bfr[nt][ks], acc[mt][nt], 0, 0, 0);
        __builtin_amdgcn_s_setprio(0);
        __builtin_amdgcn_s_barrier();

        // ---- phase 2: stage all 8 units of tile t+2; MFMA mt2-3 ----
        if (t + 2 < NT) {
            STAGE_A(c, 0, k2); STAGE_A(c, 1, k2);
            STAGE_A(c, 2, k2); STAGE_A(c, 3, k2);
            STAGE_B(c, 0, k2); STAGE_B(c, 1, k2);
            STAGE_B(c, 2, k2); STAGE_B(c, 3, k2);
        }
        __builtin_amdgcn_s_setprio(1);
        #pragma unroll
        for (int ks = 0; ks < 2; ++ks)
            #pragma unroll
            for (int mt = 2; mt < 4; ++mt)
                #pragma unroll
                for (int nt = 0; nt < 4; ++nt)
                    acc[mt][nt] = __builtin_amdgcn_mfma_f32_16x16x32_bf16(
                        af[mt][ks], bfr[nt][ks], acc[mt][nt], 0, 0, 0);
        __builtin_amdgcn_s_setprio(0);
        if (t + 2 < NT) { asm volatile("s_waitcnt vmcnt(8)" ::: "memory"); }
        else            { asm volatile("s_waitcnt vmcnt(0)" ::: "memory"); }
        __builtin_amdgcn_s_barrier();
    }

#undef STAGE_A
#undef STAGE_B

    // ---- epilogue ----
    if (widx == 2) {
        #pragma unroll
        for (int mp = 0; mp < 4; ++mp) {
            const int m0 = bm + wr * 64 + mp * 16 + quad * 4;
            const int bb = m0 >> 11;
            const int s0 = m0 & 2047;
            #pragma unroll
            for (int np = 0; np < 4; ++np) {
                const int col = bnl + wc * 64 + np * 16 + ln15;
                const float bvv = bias[col];
                ushort4 pk;
                pk.x = f2bf(acc[mp][np][0] + bvv);
                pk.y = f2bf(acc[mp][np][1] + bvv);
                pk.z = f2bf(acc[mp][np][2] + bvv);
                pk.w = f2bf(acc[mp][np][3] + bvv);
                *(ushort4*)(Vt + ((size_t)(bb * 16 + (col >> 7)) * 128 + (col & 127)) * SEQ + s0) = pk;
            }
        }
    } else {
        unsigned short* dst = widx ? Kb : Qb;
        #pragma unroll
        for (int mp = 0; mp < 4; ++mp)
            #pragma unroll
            for (int r = 0; r < 4; ++r) {
                const int row = bm + wr * 64 + mp * 16 + quad * 4 + r;
                #pragma unroll
                for (int np = 0; np < 4; ++np) {
                    const int col = bnl + wc * 64 + np * 16 + ln15;
                    dst[(size_t)row * DMODEL + col] = f2bf(acc[mp][np][r] + bias[col]);
                }
            }
    }
}

// ---------------------------------------------------------------------------
// Out-projection GEMM — 128x256 BK=64 2-phase counted-vmcnt structure,
// fp32 epilogue. 256 blocks = exactly 1 round. Unchanged (isolation).
// ---------------------------------------------------------------------------
__global__ __launch_bounds__(512, 2) void gemm_out256_kernel(
    const unsigned short* __restrict__ A, const unsigned short* __restrict__ Bt,
    const float* __restrict__ bias, float* __restrict__ C)
{
    constexpr int K  = DMODEL;   // 2048
    constexpr int N  = DMODEL;   // 2048
    constexpr int NT = K / 64;   // 32 K-tiles

    __shared__ __align__(16) unsigned short As[2][128 * 64];   // 32 KB
    __shared__ __align__(16) unsigned short Bs[2][256 * 64];   // 64 KB

    const int tid  = threadIdx.x;
    const int lane = tid & 63;
    const int wave = tid >> 6;      // 0..7
    const int ln15 = lane & 15;
    const int quad = lane >> 4;
    const int wr   = wave >> 2;     // 0..1  (M half)
    const int wc   = wave & 3;      // 0..3  (N quarter)

    const int bx = blockIdx.x & 7;         // N tile (XCD-pinned)
    const int by = blockIdx.x >> 3;        // M tile
    const int bm = by * 128;
    const int bn = bx * 256;

    const int sr = tid >> 3;
    const int sg = (tid & 7) ^ (sr & 7);
    const unsigned short* Ag = A  + (size_t)(bm + sr) * K + sg * 8;
    const unsigned short* Bg = Bt + (size_t)(bn + sr) * K + sg * 8;

    const int swz0 = ((0 + quad) ^ (ln15 & 7)) * 8;
    const int swz1 = ((4 + quad) ^ (ln15 & 7)) * 8;
    const int arow = (wr * 64 + ln15) * 64;
    const int brow = (wc * 64 + ln15) * 64;

#define STAGE_A(c, q, k0) async_load16(Ag + (size_t)(q) * 64 * K + (k0), \
                                       &As[c][(q) * 4096 + wave * 512])
#define STAGE_B(c, q, k0) async_load16(Bg + (size_t)(q) * 64 * K + (k0), \
                                       &Bs[c][(q) * 4096 + wave * 512])

    f32x4 acc[4][4];
    #pragma unroll
    for (int i = 0; i < 4; ++i)
        #pragma unroll
        for (int j = 0; j < 4; ++j) acc[i][j] = (f32x4){0.f, 0.f, 0.f, 0.f};

    STAGE_A(0, 0, 0); STAGE_A(0, 1, 0);
    STAGE_B(0, 0, 0); STAGE_B(0, 1, 0); STAGE_B(0, 2, 0); STAGE_B(0, 3, 0);
    STAGE_A(1, 0, 64); STAGE_A(1, 1, 64);
    STAGE_B(1, 0, 64); STAGE_B(1, 1, 64); STAGE_B(1, 2, 64); STAGE_B(1, 3, 64);
    asm volatile("s_waitcnt vmcnt(6)" ::: "memory");
    __builtin_amdgcn_s_barrier();

    short8 af[4][2];
    short8 bfr[4][2];

    #pragma unroll 2
    for (int t = 0; t < NT; ++t) {
        const int c  = t & 1;
        const int k2 = (t + 2) * 64;
        const unsigned short* Ac = As[c];
        const unsigned short* Bc = Bs[c];

        #pragma unroll
        for (int np = 0; np < 4; ++np) {
            bfr[np][0] = *(const short8*)(Bc + brow + np * 1024 + swz0);
            bfr[np][1] = *(const short8*)(Bc + brow + np * 1024 + swz1);
        }
        #pragma unroll
        for (int mp = 0; mp < 4; ++mp) {
            af[mp][0] = *(const short8*)(Ac + arow + mp * 1024 + swz0);
            af[mp][1] = *(const short8*)(Ac + arow + mp * 1024 + swz1);
        }
        __builtin_amdgcn_s_barrier();
        asm volatile("s_waitcnt lgkmcnt(0)" ::: "memory");
        __builtin_amdgcn_sched_barrier(0);
        __builtin_amdgcn_s_setprio(1);
        #pragma unroll
        for (int ks = 0; ks < 2; ++ks)
            #pragma unroll
            for (int mt = 0; mt < 2; ++mt)
                #pragma unroll
                for (int nt = 0; nt < 4; ++nt)
                    acc[mt][nt] = __builtin_amdgcn_mfma_f32_16x16x32_bf16(
                        af[mt][ks], bfr[nt][ks], acc[mt][nt], 0, 0, 0);
        __builtin_amdgcn_s_setprio(0);
        __builtin_amdgcn_s_barrier();

        if (t + 2 < NT) {
            STAGE_A(c, 0, k2); STAGE_A(c, 1, k2);
            STAGE_B(c, 0, k2); STAGE_B(c, 1, k2);
            STAGE_B(c, 2, k2); STAGE_B(c, 3, k2);
        }
        __builtin_amdgcn_s_setprio(1);
        #pragma unroll
        for (int ks = 0; ks < 2; ++ks)
            #pragma unroll
            for (int mt = 2; mt < 4; ++mt)
                #pragma unroll
                for (int nt = 0; nt < 4; ++nt)
                    acc[mt][nt] = __builtin_amdgcn_mfma_f32_16x16x32_bf16(
                        af[mt][ks], bfr[nt][ks], acc[mt][nt], 0, 0, 0);
        __builtin_amdgcn_s_setprio(0);
        if (t + 2 < NT) { asm volatile("s_waitcnt vmcnt(6)" ::: "memory"); }
        else            { asm volatile("s_waitcnt vmcnt(0)" ::: "memory"); }
        __builtin_amdgcn_s_barrier();
    }

#undef STAGE_A
#undef STAGE_B

    #pragma unroll
    for (int mp = 0; mp < 4; ++mp)
        #pragma unroll
        for (int r = 0; r < 4; ++r) {
            const int row = bm + wr * 64 + mp * 16 + quad * 4 + r;
            #pragma unroll
            for (int np = 0; np < 4; ++np) {
                const int col = bn + wc * 64 + np * 16 + ln15;
                C[(size_t)row * N + col] = acc[mp][np][r] + bias[col];
            }
        }
}

// ---------------------------------------------------------------------------
// MFMA flash attention — LDS-staged, double-buffered, fast-path/diagonal
// split, XCD-pinned. 1024 single-qblk blocks, 4 blocks/CU.
// Round 5: per-CU-balanced qblk permutation. All 1024 blocks co-reside;
// with round-robin dispatch CU slot c (0..7 within its dispatch octet) hosts
// the 4 blocks with j = {c, 8+c, 16+c, 24+c}. Map those to qblks
// {31-c, 16+c, 15-c, c} -> per-CU work sum == 62 for every c (was 52..80,
// a 1.3x tail). XCD pinning (g = id&31, XCD = id&7) unchanged.
// ---------------------------------------------------------------------------
#define ATT_P_STRIDE 40

__global__ __launch_bounds__(256, 4) void attn_kernel(
    const unsigned short* __restrict__ Qb, const unsigned short* __restrict__ Kb,
    const unsigned short* __restrict__ Vt,   // [B*H][HDIM][SEQ]
    unsigned short* __restrict__ O)
{
    __shared__ __align__(16) unsigned short Ks[2][32 * 128];
    __shared__ __align__(16) unsigned short Vs[2][128 * 32];
    __shared__ __align__(16) unsigned short Pl[4 * 16 * ATT_P_STRIDE];

    const int tid  = threadIdx.x;
    const int lane = tid & 63;
    const int wave = tid >> 6;
    const int ln15 = lane & 15;
    const int quad = lane >> 4;

    // XCD pinning + per-CU load balance
    const int g  = blockIdx.x & 31;
    const int j  = blockIdx.x >> 5;        // 0..31
    const int r_ = j >> 3;
    const int c_ = j & 7;
    const int qblk = r_ == 0 ? 31 - c_ : (r_ == 1 ? 16 + c_ : (r_ == 2 ? 15 - c_ : c_));
    const int h = g & 15;
    const int b = g >> 4;

    const size_t rowbase = (size_t)b * SEQ;
    const size_t hoff    = (size_t)h * HDIM;
    const unsigned short* Kh  = Kb + rowbase * DMODEL + hoff;
    const unsigned short* Vth = Vt + (size_t)(b * NHEADS + h) * HDIM * SEQ;

    const float sc2     = 0.08838834764831845f * 1.4426950408889634f;
    const float slope2  = exp2f(-0.5f * (float)(h + 1)) * 1.4426950408889634f;
    const float slope16 = slope2 * 16.0f;
    const float slope32 = slope2 * 32.0f;

    // staging lane roles
    const int kq  = wave * 8 + (lane >> 4);
    const int ksl = lane & 15;
    const int dq  = wave * 32 + (lane >> 2);
    const int vsl = lane & 3;
    const int vsw = (ln15 >> 1) & 3;

    unsigned short* Pw = &Pl[wave * 16 * ATT_P_STRIDE];

    const int q0w  = qblk * 64 + wave * 16;
    const int nT   = 2 * qblk + 2;

    short8 qf[4];
    {
        const unsigned short* qp =
            Qb + (rowbase + q0w + ln15) * DMODEL + hoff + quad * 8;
        qf[0] = *(const short8*)(qp);
        qf[1] = *(const short8*)(qp + 32);
        qf[2] = *(const short8*)(qp + 64);
        qf[3] = *(const short8*)(qp + 96);
    }

    f32x4 acc[8];
    #pragma unroll
    for (int nt = 0; nt < 8; ++nt) acc[nt] = (f32x4){0.f, 0.f, 0.f, 0.f};
    float lsum[4] = {0.f, 0.f, 0.f, 0.f};

    // incremental ALiBi bias: c0[r] = slope2*(kb+ln15 - (q0w+quad*4+r))
    float c0[4];
    {
        const float base = slope2 * (float)(ln15 - q0w - quad * 4);
        #pragma unroll
        for (int r = 0; r < 4; ++r) c0[r] = base - slope2 * (float)r;
    }

    // ---- stage tile 0 into buffer 0 ----
    #pragma unroll
    for (int i = 0; i < 2; ++i) {
        const int k = kq + i * 4;
        async_load16(Kh + (size_t)k * DMODEL + (ksl ^ (k & 15)) * 8,
                     &Ks[0][(wave * 8 + i * 4) * 128]);
    }
    #pragma unroll
    for (int i = 0; i < 2; ++i) {
        const int d = dq + i * 16;
        async_load16(Vth + (size_t)d * SEQ + (vsl ^ ((d >> 1) & 3)) * 8,
                     &Vs[0][(wave * 32 + i * 16) * 32]);
    }
    __syncthreads();

    for (int t = 0; t < nT; ++t) {
        const int kb  = t * 32;
        const int buf = t & 1;

        if (t + 1 < nT) {
            const int kb1 = kb + 32;
            #pragma unroll
            for (int i = 0; i < 2; ++i) {
                const int k = kq + i * 4;
                async_load16(Kh + (size_t)(kb1 + k) * DMODEL + (ksl ^ (k & 15)) * 8,
                             &Ks[buf ^ 1][(wave * 8 + i * 4) * 128]);
            }
            #pragma unroll
            for (int i = 0; i < 2; ++i) {
                const int d = dq + i * 16;
                async_load16(Vth + (size_t)d * SEQ + kb1 + (vsl ^ ((d >> 1) & 3)) * 8,
                             &Vs[buf ^ 1][(wave * 32 + i * 16) * 32]);
            }
        }

        if (kb <= q0w + 15) {
            const unsigned short* KsB = Ks[buf];
            const unsigned short* VsB = Vs[buf];

            f32x4 s0 = (f32x4){0.f,0.f,0.f,0.f}, s1 = (f32x4){0.f,0.f,0.f,0.f};
            #pragma unroll
            for (int c = 0; c < 4; ++c) {
                const int slot = (c * 4 + quad) ^ ln15;
                short8 kf0 = *(const short8*)(&KsB[ln15 * 128 + slot * 8]);
                short8 kf1 = *(const short8*)(&KsB[(16 + ln15) * 128 + slot * 8]);
                s0 = __builtin_amdgcn_mfma_f32_16x16x32_bf16(qf[c], kf0, s0, 0, 0, 0);
                s1 = __builtin_amdgcn_mfma_f32_16x16x32_bf16(qf[c], kf1, s1, 0, 0, 0);
            }

            float p0[4], p1[4];
            if (kb + 31 <= q0w) {
                // fully unmasked fast path
                #pragma unroll
                for (int r = 0; r < 4; ++r) {
                    p0[r] = exp2f(fmaf(s0[r], sc2, c0[r]));
                    p1[r] = exp2f(fmaf(s1[r], sc2, c0[r] + slope16));
                    lsum[r] += p0[r] + p1[r];
                }
            } else {
                // diagonal tile: per-element causal mask
                #pragma unroll
                for (int r = 0; r < 4; ++r) {
                    const int qrow = q0w + quad * 4 + r;
                    const int k0i = kb + ln15;
                    const float e0 = exp2f(fmaf(s0[r], sc2, c0[r]));
                    const float e1 = exp2f(fmaf(s1[r], sc2, c0[r] + slope16));
                    p0[r] = (k0i      <= qrow) ? e0 : 0.f;
                    p1[r] = (k0i + 16 <= qrow) ? e1 : 0.f;
                    lsum[r] += p0[r] + p1[r];
                }
            }

            #pragma unroll
            for (int r = 0; r < 4; ++r) {
                Pw[(quad * 4 + r) * ATT_P_STRIDE + ln15]      = f2bf(p0[r]);
                Pw[(quad * 4 + r) * ATT_P_STRIDE + 16 + ln15] = f2bf(p1[r]);
            }
            __builtin_amdgcn_s_waitcnt(0xC07F);   // lgkmcnt(0)
            short8 pf = *(const short8*)(&Pw[ln15 * ATT_P_STRIDE + quad * 8]);

            #pragma unroll
            for (int nt = 0; nt < 8; ++nt) {
                short8 vf = *(const short8*)(
                    &VsB[(nt * 16 + ln15) * 32 + (quad ^ vsw) * 8]);
                acc[nt] = __builtin_amdgcn_mfma_f32_16x16x32_bf16(pf, vf, acc[nt], 0, 0, 0);
            }
        }

        #pragma unroll
        for (int r = 0; r < 4; ++r) c0[r] += slope32;
        __syncthreads();
    }

    #pragma unroll
    for (int r = 0; r < 4; ++r) {
        float l = lsum[r];
        l += __shfl_xor(l, 1, 64);
        l += __shfl_xor(l, 2, 64);
        l += __shfl_xor(l, 4, 64);
        l += __shfl_xor(l, 8, 64);
        const float inv = 1.0f / l;
        const size_t ob = (rowbase + q0w + quad * 4 + r) * DMODEL + hoff;
        #pragma unroll
        for (int nt = 0; nt < 8; ++nt)
            O[ob + nt * 16 + ln15] = f2bf(acc[nt][r] * inv);
    }
}

// ---------------------------------------------------------------------------
extern "C" void kernel_launch(void* const* d_in, const int* in_sizes, int n_in,
                              void* d_out, int out_size, void* d_ws, size_t ws_size,
                              hipStream_t stream)
{
    const float* x  = (const float*)d_in[0];
    const float* wq = (const float*)d_in[1];
    const float* bq = (const float*)d_in[2];
    const float* wk = (const float*)d_in[3];
    const float* bk = (const float*)d_in[4];
    const float* wv = (const float*)d_in[5];
    const float* bv = (const float*)d_in[6];
    const float* wo = (const float*)d_in[7];
    const float* bo = (const float*)d_in[8];
    float* out = (float*)d_out;

    const size_t bufElems = (size_t)MROWS * DMODEL;   // 8.39M
    unsigned short* Qb  = (unsigned short*)d_ws;
    unsigned short* Kb  = Qb + bufElems;
    unsigned short* Vtg = Kb + bufElems;      // V^T: [B*H][HDIM][SEQ]
    unsigned short* xb  = Vtg + bufElems;     // x bf16; later reused as Ob
    unsigned short* Ob  = xb;                 // alias (xb dead after QKV GEMM)
    unsigned short* Wt  = xb + bufElems;      // 3 slots of 2048*2048 bf16

    const dim3 blk(256);

    convert_bf16_kernel<<<dim3((int)(bufElems / 1024)), blk, 0, stream>>>(
        x, xb, (int)bufElems);

    transpose3_bf16_kernel<<<dim3(32, 32, 3), blk, 0, stream>>>(wq, wk, wv, Wt);

    qkv_gemm128_kernel<<<dim3(1536), dim3(256), 0, stream>>>(
        xb, Wt, bq, bk, bv, Qb, Kb, Vtg);

    // wo -> Wt slot 0 (QKV GEMM has consumed it by stream order)
    transpose_bf16_kernel<<<dim3(32, 32), blk, 0, stream>>>(wo, Wt, DMODEL, DMODEL);

    attn_kernel<<<dim3(1024), blk, 0, stream>>>(Qb, Kb, Vtg, Ob);

    gemm_out256_kernel<<<dim3(256), dim3(512), 0, stream>>>(
        Ob, Wt, bo, out);
}